// Round 1
// baseline (4724.330 us; speedup 1.0000x reference)
//
#include <hip/hip_runtime.h>
#include <math.h>

#define BATCH 64
#define SEQ   256
#define CH    384
#define NHEAD 8
#define HD    48
#define DEPTH 6
#define NTOK  (BATCH*SEQ)   // 16384
#define C3    (3*CH)        // 1152
#define LN_EPS 1e-5f
#define ATT_SCALE 0.14433756729740643f  // 48^-0.5

// ---------------- rope cos/sin table: tbl[pos][j] = (cos, sin), j<24 ----------------
__global__ void rope_table_kernel(float2* __restrict__ tbl) {
    int pos = threadIdx.x;  // 256 threads, 1 block
    for (int j = 0; j < 24; ++j) {
        // inv_freq[j] = 10000^(-j/24) = 2^(-j*log2(10000)/24)
        float freq = exp2f(-(float)j * (13.287712379549449f / 24.0f));
        float ang = (float)pos * freq;
        float s, c;
        sincosf(ang, &s, &c);
        tbl[pos*24 + j] = make_float2(c, s);
    }
}

// ---------------- embed stage 1: y[m][c] = relu(x[m]·w1[c] + b1[c]) ----------------
__global__ void embed1_kernel(const float* __restrict__ x, const float* __restrict__ w1,
                              const float* __restrict__ b1, float* __restrict__ out) {
    int idx = blockIdx.x*256 + threadIdx.x;   // < NTOK*CH
    int m = idx / CH, c = idx - m*CH;
    float v = x[m*2]*w1[c*2] + x[m*2+1]*w1[c*2+1] + b1[c];
    out[idx] = fmaxf(v, 0.f);
}

// ---------------- LayerNorm: one wave per row of 384 ----------------
__global__ __launch_bounds__(256) void ln_kernel(const float* __restrict__ in,
        const float* __restrict__ gam, const float* __restrict__ bet,
        float* __restrict__ out) {
    int row  = blockIdx.x*4 + (threadIdx.x >> 6);
    int lane = threadIdx.x & 63;
    const float* p = in + (size_t)row*CH;
    float v[6];
    float sum = 0.f;
    #pragma unroll
    for (int i = 0; i < 6; ++i) { v[i] = p[lane + i*64]; sum += v[i]; }
    #pragma unroll
    for (int off = 1; off < 64; off <<= 1) sum += __shfl_xor(sum, off);
    float mu = sum * (1.0f/CH);
    float vs = 0.f;
    #pragma unroll
    for (int i = 0; i < 6; ++i) { float d = v[i]-mu; vs += d*d; }
    #pragma unroll
    for (int off = 1; off < 64; off <<= 1) vs += __shfl_xor(vs, off);
    float inv = rsqrtf(vs*(1.0f/CH) + LN_EPS);
    float* q = out + (size_t)row*CH;
    #pragma unroll
    for (int i = 0; i < 6; ++i) {
        int c = lane + i*64;
        q[c] = (v[i]-mu)*inv*gam[c] + bet[c];
    }
}

// ---------------- generic fp32 NT-GEMM: out = [relu](A @ W^T + bias) [+ resid] ----------------
// A: [M][lda] (uses cols 0..K-1), W: [N][K] row-major. Tile 64x64x32, 256 thr, 4x4 micro.
template<bool RELU>
__global__ __launch_bounds__(256) void gemm_nt_kernel(
        const float* __restrict__ A, int lda,
        const float* __restrict__ W,
        const float* __restrict__ bias,
        const float* resid, int ldr,
        float* out, int ldo,
        int K) {
    __shared__ float As[64][36];
    __shared__ float Ws[64][36];
    int tid = threadIdx.x;
    int m0 = blockIdx.y*64, n0 = blockIdx.x*64;
    int tx = tid & 15, ty = tid >> 4;
    float acc[4][4] = {};
    for (int k0 = 0; k0 < K; k0 += 32) {
        #pragma unroll
        for (int p = 0; p < 2; ++p) {
            int idx = tid + p*256;
            int r = idx >> 3, c4 = (idx & 7)*4;
            float4 av = *(const float4*)(A + (size_t)(m0+r)*lda + k0 + c4);
            float4 wv = *(const float4*)(W + (size_t)(n0+r)*K + k0 + c4);
            *(float4*)&As[r][c4] = av;
            *(float4*)&Ws[r][c4] = wv;
        }
        __syncthreads();
        #pragma unroll
        for (int kk = 0; kk < 32; kk += 4) {
            float4 a4[4], w4[4];
            #pragma unroll
            for (int i = 0; i < 4; ++i) a4[i] = *(const float4*)&As[ty + i*16][kk];
            #pragma unroll
            for (int j = 0; j < 4; ++j) w4[j] = *(const float4*)&Ws[tx + j*16][kk];
            #pragma unroll
            for (int i = 0; i < 4; ++i)
                #pragma unroll
                for (int j = 0; j < 4; ++j)
                    acc[i][j] += a4[i].x*w4[j].x + a4[i].y*w4[j].y
                               + a4[i].z*w4[j].z + a4[i].w*w4[j].w;
        }
        __syncthreads();
    }
    #pragma unroll
    for (int i = 0; i < 4; ++i) {
        int m = m0 + ty + i*16;
        #pragma unroll
        for (int j = 0; j < 4; ++j) {
            int n = n0 + tx + j*16;
            float v = acc[i][j];
            if (bias)  v += bias[n];
            if (RELU)  v = fmaxf(v, 0.f);
            if (resid) v += resid[(size_t)m*ldr + n];
            out[(size_t)m*ldo + n] = v;
        }
    }
}

// ---------------- attention: one block per (b, head); thread = query row ----------------
// K staged in LDS with RoPE; V read from global (uniform broadcast, L2-resident).
// O written into the q-region of qkv (cols h*HD..), giving (B,N,C) layout at lda=C3.
__global__ __launch_bounds__(256) void attn_kernel(
        float* qkv, const float* __restrict__ mask,
        const float2* __restrict__ tbl) {
    int b  = blockIdx.x >> 3;
    int hh = blockIdx.x & 7;
    __shared__ float Ks[SEQ*HD];   // 48 KB
    __shared__ float Ms[SEQ];      // 1 KB
    int t = threadIdx.x;           // query / key row
    size_t rowbase = ((size_t)(b*SEQ + t))*C3;
    float* qp       = qkv + rowbase + hh*HD;
    const float* kp = qkv + rowbase + CH + hh*HD;
    float qr[HD], kr[HD];
    #pragma unroll
    for (int d4 = 0; d4 < HD; d4 += 4) {
        *(float4*)&qr[d4] = *(const float4*)(qp + d4);
        *(float4*)&kr[d4] = *(const float4*)(kp + d4);
    }
    // rope (pos = t), q also scaled
    #pragma unroll
    for (int j = 0; j < 24; ++j) {
        float2 cs = tbl[t*24 + j];
        float qu = qr[2*j], qe = qr[2*j+1];
        qr[2*j]   = (qu*cs.x - qe*cs.y) * ATT_SCALE;
        qr[2*j+1] = (qu*cs.y + qe*cs.x) * ATT_SCALE;
        float ku = kr[2*j], ke = kr[2*j+1];
        kr[2*j]   = ku*cs.x - ke*cs.y;
        kr[2*j+1] = ku*cs.y + ke*cs.x;
    }
    #pragma unroll
    for (int d4 = 0; d4 < HD; d4 += 4)
        *(float4*)&Ks[t*HD + d4] = *(const float4*)&kr[d4];
    Ms[t] = mask[b*SEQ + t];
    __syncthreads();

    const float* vbase = qkv + (size_t)b*SEQ*C3 + 2*CH + hh*HD;
    float m_run = -1e30f, l_run = 0.f;
    float oacc[HD] = {};
    for (int k = 0; k < SEQ; ++k) {
        const float* kk = Ks + k*HD;
        float s = Ms[k];
        #pragma unroll
        for (int d = 0; d < HD; ++d) s += qr[d]*kk[d];
        float m_new = fmaxf(m_run, s);
        float corr = __expf(m_run - m_new);
        float p    = __expf(s - m_new);
        l_run = l_run*corr + p;
        const float* vv = vbase + (size_t)k*C3;
        #pragma unroll
        for (int d4 = 0; d4 < HD; d4 += 4) {
            float4 v4 = *(const float4*)(vv + d4);
            oacc[d4+0] = oacc[d4+0]*corr + p*v4.x;
            oacc[d4+1] = oacc[d4+1]*corr + p*v4.y;
            oacc[d4+2] = oacc[d4+2]*corr + p*v4.z;
            oacc[d4+3] = oacc[d4+3]*corr + p*v4.w;
        }
        m_run = m_new;
    }
    float inv = 1.f/l_run;
    #pragma unroll
    for (int d = 0; d < HD; ++d) qp[d] = oacc[d]*inv;
}

// ---------------- launcher ----------------
extern "C" void kernel_launch(void* const* d_in, const int* in_sizes, int n_in,
                              void* d_out, int out_size, void* d_ws, size_t ws_size,
                              hipStream_t stream) {
    const float* x      = (const float*)d_in[0];
    const float* mask   = (const float*)d_in[1];
    const float* emb_w1 = (const float*)d_in[2];
    const float* emb_b1 = (const float*)d_in[3];
    const float* emb_w2 = (const float*)d_in[4];
    const float* emb_b2 = (const float*)d_in[5];
    const float* qkv_w  = (const float*)d_in[6];
    const float* proj_w = (const float*)d_in[7];
    const float* proj_b = (const float*)d_in[8];
    const float* mlp_w1 = (const float*)d_in[9];
    const float* mlp_b1 = (const float*)d_in[10];
    const float* mlp_w2 = (const float*)d_in[11];
    const float* mlp_b2 = (const float*)d_in[12];
    const float* ln1_s  = (const float*)d_in[13];
    const float* ln1_b  = (const float*)d_in[14];
    const float* ln2_s  = (const float*)d_in[15];
    const float* ln2_b  = (const float*)d_in[16];

    const size_t S1 = (size_t)NTOK*CH;      // 6291456
    float* ws  = (float*)d_ws;
    float* h   = ws;                        // [NTOK][CH]
    float* y   = h  + S1;                   // [NTOK][CH]  (LN out / embed tmp)
    float* t2  = y  + S1;                   // [NTOK][CH]  (mlp hidden)
    float* qkv = t2 + S1;                   // [NTOK][C3]  (o overwrites q-region)
    float* tbl = qkv + 3*S1;                // float2[256][24]

    dim3 g6(CH/64,  NTOK/64);   // 6 x 256
    dim3 g18(C3/64, NTOK/64);   // 18 x 256

    rope_table_kernel<<<1, 256, 0, stream>>>((float2*)tbl);
    embed1_kernel<<<(NTOK*CH)/256, 256, 0, stream>>>(x, emb_w1, emb_b1, y);
    gemm_nt_kernel<false><<<g6, 256, 0, stream>>>(y, CH, emb_w2, emb_b2,
                                                  nullptr, 0, h, CH, CH);
    for (int i = 0; i < DEPTH; ++i) {
        ln_kernel<<<NTOK/4, 256, 0, stream>>>(h, ln1_s + i*CH, ln1_b + i*CH, y);
        gemm_nt_kernel<false><<<g18, 256, 0, stream>>>(y, CH, qkv_w + (size_t)i*C3*CH,
                                                       nullptr, nullptr, 0, qkv, C3, CH);
        attn_kernel<<<BATCH*NHEAD, 256, 0, stream>>>(qkv, mask, (const float2*)tbl);
        gemm_nt_kernel<false><<<g6, 256, 0, stream>>>(qkv, C3, proj_w + (size_t)i*CH*CH,
                                                      proj_b + i*CH, h, CH, h, CH, CH);
        ln_kernel<<<NTOK/4, 256, 0, stream>>>(h, ln2_s + i*CH, ln2_b + i*CH, y);
        gemm_nt_kernel<true><<<g6, 256, 0, stream>>>(y, CH, mlp_w1 + (size_t)i*CH*CH,
                                                     mlp_b1 + i*CH, nullptr, 0, t2, CH, CH);
        gemm_nt_kernel<false><<<g6, 256, 0, stream>>>(t2, CH, mlp_w2 + (size_t)i*CH*CH,
                                                      mlp_b2 + i*CH, h, CH, h, CH, CH);
    }
    hipMemcpyAsync(d_out, h, S1*sizeof(float), hipMemcpyDeviceToDevice, stream);
}

// Round 2
// 2064.977 us; speedup vs baseline: 2.2878x; 2.2878x over previous
//
#include <hip/hip_runtime.h>
#include <hip/hip_bf16.h>
#include <math.h>

#define BATCH 64
#define SEQ   256
#define CH    384
#define NHEAD 8
#define HD    48
#define DEPTH 6
#define NTOK  (BATCH*SEQ)   // 16384
#define C3    (3*CH)        // 1152
#define LN_EPS 1e-5f
#define ATT_SCALE 0.14433756729740643f  // 48^-0.5

typedef __attribute__((ext_vector_type(8))) short bf16x8;
typedef __attribute__((ext_vector_type(4))) float f32x4;

__device__ __forceinline__ ushort f2bf(float f) {
    __hip_bfloat16 h = __float2bfloat16(f);
    return *(ushort*)&h;
}
__device__ __forceinline__ float bf2f(ushort u) {
    __hip_bfloat16 h = *(__hip_bfloat16*)&u;
    return __bfloat162float(h);
}

#define AS1(p) ((const __attribute__((address_space(1))) void*)(p))
#define AS3(p) ((__attribute__((address_space(3))) void*)(uintptr_t)(p))

// ---------------- fp32 -> bf16 bulk convert (n divisible by 1024) ----------------
__global__ void f2bf4_kernel(const float* __restrict__ in, ushort* __restrict__ out) {
    int i = (blockIdx.x*256 + threadIdx.x)*4;
    float4 v = *(const float4*)(in + i);
    ushort4 o;
    o.x = f2bf(v.x); o.y = f2bf(v.y); o.z = f2bf(v.z); o.w = f2bf(v.w);
    *(ushort4*)(out + i) = o;
}

// ---------------- rope cos/sin table ----------------
__global__ void rope_table_kernel(float2* __restrict__ tbl) {
    int pos = threadIdx.x;
    for (int j = 0; j < 24; ++j) {
        float freq = exp2f(-(float)j * (13.287712379549449f / 24.0f));
        float ang = (float)pos * freq;
        float s, c;
        sincosf(ang, &s, &c);
        tbl[pos*24 + j] = make_float2(c, s);
    }
}

// ---------------- embed stage 1 -> bf16 ----------------
__global__ void embed1_kernel(const float* __restrict__ x, const float* __restrict__ w1,
                              const float* __restrict__ b1, ushort* __restrict__ out) {
    int idx = blockIdx.x*256 + threadIdx.x;
    int m = idx / CH, c = idx - m*CH;
    float v = x[m*2]*w1[c*2] + x[m*2+1]*w1[c*2+1] + b1[c];
    out[idx] = f2bf(fmaxf(v, 0.f));
}

// ---------------- LayerNorm fp32 -> bf16 ----------------
__global__ __launch_bounds__(256) void ln_kernel(const float* __restrict__ in,
        const float* __restrict__ gam, const float* __restrict__ bet,
        ushort* __restrict__ out) {
    int row  = blockIdx.x*4 + (threadIdx.x >> 6);
    int lane = threadIdx.x & 63;
    const float* p = in + (size_t)row*CH;
    float v[6];
    float sum = 0.f;
    #pragma unroll
    for (int i = 0; i < 6; ++i) { v[i] = p[lane + i*64]; sum += v[i]; }
    #pragma unroll
    for (int off = 1; off < 64; off <<= 1) sum += __shfl_xor(sum, off);
    float mu = sum * (1.0f/CH);
    float vs = 0.f;
    #pragma unroll
    for (int i = 0; i < 6; ++i) { float d = v[i]-mu; vs += d*d; }
    #pragma unroll
    for (int off = 1; off < 64; off <<= 1) vs += __shfl_xor(vs, off);
    float inv = rsqrtf(vs*(1.0f/CH) + LN_EPS);
    ushort* q = out + (size_t)row*CH;
    #pragma unroll
    for (int i = 0; i < 6; ++i) {
        int c = lane + i*64;
        q[c] = f2bf((v[i]-mu)*inv*gam[c] + bet[c]);
    }
}

// ---------------- bf16 MFMA NT-GEMM (m97 structure, 128x128 tile, BK=32) ----------------
// A: [M][lda] bf16; W: [N][ldw] bf16 (row-major, uses cols 0..K-1).
// out = [relu](A@W^T + bias) [+ resid]; fp32 or bf16 out.
template<bool RELU, bool BF16OUT>
__global__ __launch_bounds__(256) void gemm_bf16_kernel(
        const ushort* __restrict__ A, int lda,
        const ushort* __restrict__ W, int ldw,
        const float* __restrict__ bias,
        const float* __restrict__ resid,
        void* __restrict__ out, int ldo,
        int K) {
    __shared__ __align__(16) ushort As[128*32];   // 8 KB
    __shared__ __align__(16) ushort Bs[128*32];   // 8 KB
    const int tid  = threadIdx.x;
    const int lane = tid & 63;
    const int w    = tid >> 6;             // wave 0..3
    const int wr   = (w >> 1) * 64;        // wave row offset in tile
    const int wc   = (w & 1) * 64;         // wave col offset in tile
    const int m0   = blockIdx.y * 128;
    const int n0   = blockIdx.x * 128;

    f32x4 acc[4][4] = {};

    for (int k0 = 0; k0 < K; k0 += 32) {
        if (k0) __syncthreads();
        // stage 16 KB via global_load_lds width 16: 16 chunks of 1 KB, 4 per wave
        #pragma unroll
        for (int c = 0; c < 4; ++c) {
            int chunk = w*4 + c;
            if (chunk < 8) {
                int row = chunk*16 + (lane >> 2);
                const ushort* gp = A + (size_t)(m0+row)*lda + k0 + (lane & 3)*8;
                __builtin_amdgcn_global_load_lds(AS1(gp), AS3(&As[chunk*512]), 16, 0, 0);
            } else {
                int row = (chunk-8)*16 + (lane >> 2);
                const ushort* gp = W + (size_t)(n0+row)*ldw + k0 + (lane & 3)*8;
                __builtin_amdgcn_global_load_lds(AS1(gp), AS3(&Bs[(chunk-8)*512]), 16, 0, 0);
            }
        }
        __syncthreads();
        bf16x8 a[4], b[4];
        #pragma unroll
        for (int i = 0; i < 4; ++i)
            a[i] = *(const bf16x8*)&As[(wr + i*16 + (lane & 15))*32 + 8*(lane >> 4)];
        #pragma unroll
        for (int j = 0; j < 4; ++j)
            b[j] = *(const bf16x8*)&Bs[(wc + j*16 + (lane & 15))*32 + 8*(lane >> 4)];
        #pragma unroll
        for (int i = 0; i < 4; ++i)
            #pragma unroll
            for (int j = 0; j < 4; ++j)
                acc[i][j] = __builtin_amdgcn_mfma_f32_16x16x32_bf16(a[i], b[j], acc[i][j], 0, 0, 0);
    }

    // epilogue: C row = (lane>>4)*4 + reg, col = lane&15 (HW-verified mapping)
    const int cbase = n0 + wc + (lane & 15);
    const int rbase = m0 + wr + ((lane >> 4) << 2);
    #pragma unroll
    for (int i = 0; i < 4; ++i)
        #pragma unroll
        for (int r = 0; r < 4; ++r) {
            int m = rbase + i*16 + r;
            #pragma unroll
            for (int j = 0; j < 4; ++j) {
                int n = cbase + j*16;
                float v = acc[i][j][r];
                if (bias)  v += bias[n];
                if (RELU)  v = fmaxf(v, 0.f);
                if (resid) v += resid[(size_t)m*ldo + n];
                if (BF16OUT) ((ushort*)out)[(size_t)m*ldo + n] = f2bf(v);
                else         ((float*)out)[(size_t)m*ldo + n]  = v;
            }
        }
}

// ---------------- attention (fp32 math), writes bf16 o-buffer ----------------
__global__ __launch_bounds__(256) void attn_kernel(
        const float* __restrict__ qkv, const float* __restrict__ mask,
        const float2* __restrict__ tbl, ushort* __restrict__ obuf) {
    int b  = blockIdx.x >> 3;
    int hh = blockIdx.x & 7;
    __shared__ float Ks[SEQ*HD];   // 48 KB
    __shared__ float Ms[SEQ];
    int t = threadIdx.x;
    size_t rowbase = ((size_t)(b*SEQ + t))*C3;
    const float* qp = qkv + rowbase + hh*HD;
    const float* kp = qkv + rowbase + CH + hh*HD;
    float qr[HD], kr[HD];
    #pragma unroll
    for (int d4 = 0; d4 < HD; d4 += 4) {
        *(float4*)&qr[d4] = *(const float4*)(qp + d4);
        *(float4*)&kr[d4] = *(const float4*)(kp + d4);
    }
    #pragma unroll
    for (int j = 0; j < 24; ++j) {
        float2 cs = tbl[t*24 + j];
        float qu = qr[2*j], qe = qr[2*j+1];
        qr[2*j]   = (qu*cs.x - qe*cs.y) * ATT_SCALE;
        qr[2*j+1] = (qu*cs.y + qe*cs.x) * ATT_SCALE;
        float ku = kr[2*j], ke = kr[2*j+1];
        kr[2*j]   = ku*cs.x - ke*cs.y;
        kr[2*j+1] = ku*cs.y + ke*cs.x;
    }
    #pragma unroll
    for (int d4 = 0; d4 < HD; d4 += 4)
        *(float4*)&Ks[t*HD + d4] = *(const float4*)&kr[d4];
    Ms[t] = mask[b*SEQ + t];
    __syncthreads();

    const float* vbase = qkv + (size_t)b*SEQ*C3 + 2*CH + hh*HD;
    float m_run = -1e30f, l_run = 0.f;
    float oacc[HD] = {};
    for (int k = 0; k < SEQ; ++k) {
        const float* kk = Ks + k*HD;
        float s = Ms[k];
        #pragma unroll
        for (int d = 0; d < HD; ++d) s += qr[d]*kk[d];
        float m_new = fmaxf(m_run, s);
        float corr = __expf(m_run - m_new);
        float p    = __expf(s - m_new);
        l_run = l_run*corr + p;
        const float* vv = vbase + (size_t)k*C3;
        #pragma unroll
        for (int d4 = 0; d4 < HD; d4 += 4) {
            float4 v4 = *(const float4*)(vv + d4);
            oacc[d4+0] = oacc[d4+0]*corr + p*v4.x;
            oacc[d4+1] = oacc[d4+1]*corr + p*v4.y;
            oacc[d4+2] = oacc[d4+2]*corr + p*v4.z;
            oacc[d4+3] = oacc[d4+3]*corr + p*v4.w;
        }
        m_run = m_new;
    }
    float inv = 1.f/l_run;
    ushort* op = obuf + ((size_t)(b*SEQ + t))*CH + hh*HD;
    #pragma unroll
    for (int d = 0; d < HD; ++d) op[d] = f2bf(oacc[d]*inv);
}

// ---------------- launcher ----------------
extern "C" void kernel_launch(void* const* d_in, const int* in_sizes, int n_in,
                              void* d_out, int out_size, void* d_ws, size_t ws_size,
                              hipStream_t stream) {
    const float* x      = (const float*)d_in[0];
    const float* mask   = (const float*)d_in[1];
    const float* emb_w1 = (const float*)d_in[2];
    const float* emb_b1 = (const float*)d_in[3];
    const float* emb_w2 = (const float*)d_in[4];
    const float* emb_b2 = (const float*)d_in[5];
    const float* qkv_w  = (const float*)d_in[6];
    const float* proj_w = (const float*)d_in[7];
    const float* proj_b = (const float*)d_in[8];
    const float* mlp_w1 = (const float*)d_in[9];
    const float* mlp_b1 = (const float*)d_in[10];
    const float* mlp_w2 = (const float*)d_in[11];
    const float* mlp_b2 = (const float*)d_in[12];
    const float* ln1_s  = (const float*)d_in[13];
    const float* ln1_b  = (const float*)d_in[14];
    const float* ln2_s  = (const float*)d_in[15];
    const float* ln2_b  = (const float*)d_in[16];

    const size_t S1 = (size_t)NTOK*CH;          // 6291456
    float* ws   = (float*)d_ws;
    float*  h    = ws;                          // fp32 [NTOK][CH]
    float*  qkv  = h + S1;                      // fp32 [NTOK][C3]
    ushort* ybf  = (ushort*)(qkv + 3*S1);       // bf16 [NTOK][CH]
    ushort* t2bf = ybf  + S1;                   // bf16 [NTOK][CH]
    ushort* obf  = t2bf + S1;                   // bf16 [NTOK][CH]
    ushort* wb   = obf  + S1;                   // bf16 weights
    ushort* wb_emb2 = wb;                            // 147456
    ushort* wb_qkv  = wb_emb2 + 147456;              // 6*1152*384 = 2654208
    ushort* wb_proj = wb_qkv  + 2654208;             // 884736
    ushort* wb_m1   = wb_proj + 884736;              // 884736
    ushort* wb_m2   = wb_m1   + 884736;              // 884736
    float*  tbl  = (float*)(wb_m2 + 884736);

    dim3 g6(3, 128);    // N=384
    dim3 g18(9, 128);   // N=1152

    rope_table_kernel<<<1, 256, 0, stream>>>((float2*)tbl);
    f2bf4_kernel<<<144,  256, 0, stream>>>(emb_w2, wb_emb2);
    f2bf4_kernel<<<2592, 256, 0, stream>>>(qkv_w,  wb_qkv);
    f2bf4_kernel<<<864,  256, 0, stream>>>(proj_w, wb_proj);
    f2bf4_kernel<<<864,  256, 0, stream>>>(mlp_w1, wb_m1);
    f2bf4_kernel<<<864,  256, 0, stream>>>(mlp_w2, wb_m2);

    embed1_kernel<<<(NTOK*CH)/256, 256, 0, stream>>>(x, emb_w1, emb_b1, ybf);
    gemm_bf16_kernel<false,false><<<g6, 256, 0, stream>>>(ybf, CH, wb_emb2, CH,
            emb_b2, nullptr, h, CH, CH);

    for (int i = 0; i < DEPTH; ++i) {
        ln_kernel<<<NTOK/4, 256, 0, stream>>>(h, ln1_s + i*CH, ln1_b + i*CH, ybf);
        gemm_bf16_kernel<false,false><<<g18, 256, 0, stream>>>(ybf, CH,
                wb_qkv + (size_t)i*C3*CH, CH, nullptr, nullptr, qkv, C3, CH);
        attn_kernel<<<BATCH*NHEAD, 256, 0, stream>>>(qkv, mask, (const float2*)tbl, obf);
        gemm_bf16_kernel<false,false><<<g6, 256, 0, stream>>>(obf, CH,
                wb_proj + (size_t)i*CH*CH, CH, proj_b + i*CH, h, h, CH, CH);
        ln_kernel<<<NTOK/4, 256, 0, stream>>>(h, ln2_s + i*CH, ln2_b + i*CH, ybf);
        gemm_bf16_kernel<true,true><<<g6, 256, 0, stream>>>(ybf, CH,
                wb_m1 + (size_t)i*CH*CH, CH, mlp_b1 + i*CH, nullptr, t2bf, CH, CH);
        gemm_bf16_kernel<false,false><<<g6, 256, 0, stream>>>(t2bf, CH,
                wb_m2 + (size_t)i*CH*CH, CH, mlp_b2 + i*CH, h, h, CH, CH);
    }
    hipMemcpyAsync(d_out, h, S1*sizeof(float), hipMemcpyDeviceToDevice, stream);
}

// Round 3
// 1330.592 us; speedup vs baseline: 3.5505x; 1.5519x over previous
//
#include <hip/hip_runtime.h>
#include <hip/hip_bf16.h>
#include <math.h>

#define BATCH 64
#define SEQ   256
#define CH    384
#define NHEAD 8
#define HD    48
#define DEPTH 6
#define NTOK  (BATCH*SEQ)   // 16384
#define C3    (3*CH)        // 1152
#define LN_EPS 1e-5f
#define ATT_SCALE 0.14433756729740643f  // 48^-0.5

typedef __attribute__((ext_vector_type(8)))  short bf16x8;
typedef __attribute__((ext_vector_type(4)))  float f32x4;
typedef __attribute__((ext_vector_type(16))) float f32x16;

__device__ __forceinline__ ushort f2bf(float f) {
    __hip_bfloat16 h = __float2bfloat16(f);
    return *(ushort*)&h;
}
__device__ __forceinline__ uint pk2(float a, float b) {
    return (uint)f2bf(a) | ((uint)f2bf(b) << 16);
}

#define AS1(p) ((const __attribute__((address_space(1))) void*)(p))
#define AS3(p) ((__attribute__((address_space(3))) void*)(uintptr_t)(p))

// ---------------- fp32 -> bf16 bulk convert ----------------
__global__ void f2bf4_kernel(const float* __restrict__ in, ushort* __restrict__ out) {
    int i = (blockIdx.x*256 + threadIdx.x)*4;
    float4 v = *(const float4*)(in + i);
    ushort4 o;
    o.x = f2bf(v.x); o.y = f2bf(v.y); o.z = f2bf(v.z); o.w = f2bf(v.w);
    *(ushort4*)(out + i) = o;
}

// ---------------- rope cos/sin table ----------------
__global__ void rope_table_kernel(float2* __restrict__ tbl) {
    int pos = threadIdx.x;
    for (int j = 0; j < 24; ++j) {
        float freq = exp2f(-(float)j * (13.287712379549449f / 24.0f));
        float ang = (float)pos * freq;
        float s, c;
        sincosf(ang, &s, &c);
        tbl[pos*24 + j] = make_float2(c, s);
    }
}

// ---------------- embed stage 1 -> bf16 ----------------
__global__ void embed1_kernel(const float* __restrict__ x, const float* __restrict__ w1,
                              const float* __restrict__ b1, ushort* __restrict__ out) {
    int idx = blockIdx.x*256 + threadIdx.x;
    int m = idx / CH, c = idx - m*CH;
    float v = x[m*2]*w1[c*2] + x[m*2+1]*w1[c*2+1] + b1[c];
    out[idx] = f2bf(fmaxf(v, 0.f));
}

// ---------------- LayerNorm fp32 -> bf16 ----------------
__global__ __launch_bounds__(256) void ln_kernel(const float* __restrict__ in,
        const float* __restrict__ gam, const float* __restrict__ bet,
        ushort* __restrict__ out) {
    int row  = blockIdx.x*4 + (threadIdx.x >> 6);
    int lane = threadIdx.x & 63;
    const float* p = in + (size_t)row*CH;
    float v[6];
    float sum = 0.f;
    #pragma unroll
    for (int i = 0; i < 6; ++i) { v[i] = p[lane + i*64]; sum += v[i]; }
    #pragma unroll
    for (int off = 1; off < 64; off <<= 1) sum += __shfl_xor(sum, off);
    float mu = sum * (1.0f/CH);
    float vs = 0.f;
    #pragma unroll
    for (int i = 0; i < 6; ++i) { float d = v[i]-mu; vs += d*d; }
    #pragma unroll
    for (int off = 1; off < 64; off <<= 1) vs += __shfl_xor(vs, off);
    float inv = rsqrtf(vs*(1.0f/CH) + LN_EPS);
    ushort* q = out + (size_t)row*CH;
    #pragma unroll
    for (int i = 0; i < 6; ++i) {
        int c = lane + i*64;
        q[c] = f2bf((v[i]-mu)*inv*gam[c] + bet[c]);
    }
}

// ---------------- bf16 MFMA NT-GEMM (m97 structure, 128x128 tile, BK=32) ----------------
template<bool RELU, bool BF16OUT>
__global__ __launch_bounds__(256) void gemm_bf16_kernel(
        const ushort* __restrict__ A, int lda,
        const ushort* __restrict__ W, int ldw,
        const float* __restrict__ bias,
        const float* __restrict__ resid,
        void* __restrict__ out, int ldo,
        int K) {
    __shared__ __align__(16) ushort As[128*32];
    __shared__ __align__(16) ushort Bs[128*32];
    const int tid  = threadIdx.x;
    const int lane = tid & 63;
    const int w    = tid >> 6;
    const int wr   = (w >> 1) * 64;
    const int wc   = (w & 1) * 64;
    const int m0   = blockIdx.y * 128;
    const int n0   = blockIdx.x * 128;

    f32x4 acc[4][4] = {};

    for (int k0 = 0; k0 < K; k0 += 32) {
        if (k0) __syncthreads();
        #pragma unroll
        for (int c = 0; c < 4; ++c) {
            int chunk = w*4 + c;
            if (chunk < 8) {
                int row = chunk*16 + (lane >> 2);
                const ushort* gp = A + (size_t)(m0+row)*lda + k0 + (lane & 3)*8;
                __builtin_amdgcn_global_load_lds(AS1(gp), AS3(&As[chunk*512]), 16, 0, 0);
            } else {
                int row = (chunk-8)*16 + (lane >> 2);
                const ushort* gp = W + (size_t)(n0+row)*ldw + k0 + (lane & 3)*8;
                __builtin_amdgcn_global_load_lds(AS1(gp), AS3(&Bs[(chunk-8)*512]), 16, 0, 0);
            }
        }
        __syncthreads();
        bf16x8 a[4], b[4];
        #pragma unroll
        for (int i = 0; i < 4; ++i)
            a[i] = *(const bf16x8*)&As[(wr + i*16 + (lane & 15))*32 + 8*(lane >> 4)];
        #pragma unroll
        for (int j = 0; j < 4; ++j)
            b[j] = *(const bf16x8*)&Bs[(wc + j*16 + (lane & 15))*32 + 8*(lane >> 4)];
        #pragma unroll
        for (int i = 0; i < 4; ++i)
            #pragma unroll
            for (int j = 0; j < 4; ++j)
                acc[i][j] = __builtin_amdgcn_mfma_f32_16x16x32_bf16(a[i], b[j], acc[i][j], 0, 0, 0);
    }

    const int cbase = n0 + wc + (lane & 15);
    const int rbase = m0 + wr + ((lane >> 4) << 2);
    #pragma unroll
    for (int i = 0; i < 4; ++i)
        #pragma unroll
        for (int r = 0; r < 4; ++r) {
            int m = rbase + i*16 + r;
            #pragma unroll
            for (int j = 0; j < 4; ++j) {
                int n = cbase + j*16;
                float v = acc[i][j][r];
                if (bias)  v += bias[n];
                if (RELU)  v = fmaxf(v, 0.f);
                if (resid) v += resid[(size_t)m*ldo + n];
                if (BF16OUT) ((ushort*)out)[(size_t)m*ldo + n] = f2bf(v);
                else         ((float*)out)[(size_t)m*ldo + n]  = v;
            }
        }
}

// ---------------- MFMA attention: block = (b,head), 8 waves, wave = 32 q-rows ----------------
// S^T = mfma(K, Q): lane holds q-col (lane&31), k-rows lane-local -> register softmax.
// O^T = mfma(V^T, P^T): V^T staged as fragments (d padded 48->64), P built via pk2+shfl_xor(32).
__global__ __launch_bounds__(512) void attn_kernel(
        const float* __restrict__ qkv, const float* __restrict__ mask,
        const float2* __restrict__ tbl, ushort* __restrict__ obuf) {
    __shared__ __align__(16) ushort Kf[8*3*64*8];   // 24 KB, frag order [(t*3+s)*64+L]*8
    __shared__ __align__(16) ushort Vf[2*16*64*8];  // 32 KB, frag order [(dt*16+sp)*64+L]*8
    __shared__ float Ms[SEQ];

    const int bid = blockIdx.x;
    const int b   = bid >> 3;
    const int hh  = bid & 7;
    const int tid = threadIdx.x;
    const int lane = tid & 63;
    const int hi   = (lane >> 5);        // 0/1
    const int q5   = lane & 31;
    const float* base = qkv + (size_t)b*SEQ*C3;

    // ---- stage K as QK A-fragments, rope fused; thread: t=tid>>6, row=t*32+(tid&31) ----
    {
        int t   = tid >> 6;
        int row = t*32 + q5;
        const float* kp = base + (size_t)row*C3 + CH + hh*HD;
        #pragma unroll
        for (int s = 0; s < 3; ++s) {
            float v8[8];
            *(float4*)&v8[0] = *(const float4*)(kp + s*16 + hi*8);
            *(float4*)&v8[4] = *(const float4*)(kp + s*16 + hi*8 + 4);
            union { uint w[4]; bf16x8 v; } u;
            #pragma unroll
            for (int p = 0; p < 4; ++p) {
                float2 cs = tbl[row*24 + s*8 + hi*4 + p];
                float xu = v8[2*p], xe = v8[2*p+1];
                u.w[p] = pk2(xu*cs.x - xe*cs.y, xu*cs.y + xe*cs.x);
            }
            *(bf16x8*)&Kf[((t*3 + s)*64 + lane)*8] = u.v;
        }
    }
    // ---- stage V^T as PV A-fragments (d = dt*32 + q5, zero-pad d>=48) ----
    {
        #pragma unroll
        for (int p = 0; p < 4; ++p) {
            int dt = p >> 1;
            int sp = (tid >> 6)*2 + (p & 1);
            int dd = dt*32 + q5;
            union { uint w[4]; bf16x8 v; } u;
            if (dd < HD) {
                const float* vp = base + (size_t)(sp*16 + hi*8)*C3 + 2*CH + hh*HD + dd;
                float v8[8];
                #pragma unroll
                for (int j = 0; j < 8; ++j) v8[j] = vp[j*C3];
                #pragma unroll
                for (int k = 0; k < 4; ++k) u.w[k] = pk2(v8[2*k], v8[2*k+1]);
            } else {
                u.w[0] = u.w[1] = u.w[2] = u.w[3] = 0u;
            }
            *(bf16x8*)&Vf[((dt*16 + sp)*64 + lane)*8] = u.v;
        }
    }
    if (tid < SEQ) Ms[tid] = mask[b*SEQ + tid];

    // ---- per-wave Q B-fragments (rope + scale fused) ----
    const int wv    = tid >> 6;
    const int qbase = wv * 32;
    const int qrow  = qbase + q5;
    bf16x8 qf[3];
    {
        const float* qp = base + (size_t)qrow*C3 + hh*HD;
        #pragma unroll
        for (int s = 0; s < 3; ++s) {
            float v8[8];
            *(float4*)&v8[0] = *(const float4*)(qp + s*16 + hi*8);
            *(float4*)&v8[4] = *(const float4*)(qp + s*16 + hi*8 + 4);
            union { uint w[4]; bf16x8 v; } u;
            #pragma unroll
            for (int p = 0; p < 4; ++p) {
                float2 cs = tbl[qrow*24 + s*8 + hi*4 + p];
                float xu = v8[2*p], xe = v8[2*p+1];
                u.w[p] = pk2((xu*cs.x - xe*cs.y)*ATT_SCALE, (xu*cs.y + xe*cs.x)*ATT_SCALE);
            }
            qf[s] = u.v;
        }
    }
    __syncthreads();

    // ---- S^T: 8 k-tiles x 3 d-steps ----
    f32x16 st[8] = {};
    #pragma unroll
    for (int t = 0; t < 8; ++t)
        #pragma unroll
        for (int s = 0; s < 3; ++s) {
            bf16x8 af = *(const bf16x8*)&Kf[((t*3 + s)*64 + lane)*8];
            st[t] = __builtin_amdgcn_mfma_f32_32x32x16_bf16(af, qf[s], st[t], 0, 0, 0);
        }

    // ---- register softmax (rows lane-local; one shfl_xor(32) per reduce) ----
    float mx = -1e30f;
    #pragma unroll
    for (int t = 0; t < 8; ++t)
        #pragma unroll
        for (int r = 0; r < 16; ++r) {
            int kt = t*32 + (r & 3) + 8*(r >> 2) + 4*hi;
            float s = st[t][r] + Ms[kt];
            st[t][r] = s;
            mx = fmaxf(mx, s);
        }
    mx = fmaxf(mx, __shfl_xor(mx, 32));
    float sum = 0.f;
    #pragma unroll
    for (int t = 0; t < 8; ++t)
        #pragma unroll
        for (int r = 0; r < 16; ++r) {
            float p = __expf(st[t][r] - mx);
            st[t][r] = p;
            sum += p;
        }
    sum += __shfl_xor(sum, 32);

    // ---- PV: build P B-frags in-register, O^T += V^T . P^T ----
    f32x16 oacc[2] = {};
    #pragma unroll
    for (int t = 0; t < 8; ++t) {
        uint w[4][2];
        #pragma unroll
        for (int g = 0; g < 4; ++g) {
            w[g][0] = pk2(st[t][g*4+0], st[t][g*4+1]);
            w[g][1] = pk2(st[t][g*4+2], st[t][g*4+3]);
        }
        #pragma unroll
        for (int o = 0; o < 2; ++o) {
            uint x0 = __shfl_xor(hi ? w[2*o][0] : w[2*o+1][0], 32);
            uint x1 = __shfl_xor(hi ? w[2*o][1] : w[2*o+1][1], 32);
            union { uint w[4]; bf16x8 v; } pf;
            if (hi == 0) { pf.w[0] = w[2*o][0]; pf.w[1] = w[2*o][1]; pf.w[2] = x0; pf.w[3] = x1; }
            else         { pf.w[0] = x0; pf.w[1] = x1; pf.w[2] = w[2*o+1][0]; pf.w[3] = w[2*o+1][1]; }
            int sp = t*2 + o;
            #pragma unroll
            for (int dt = 0; dt < 2; ++dt) {
                bf16x8 vf = *(const bf16x8*)&Vf[((dt*16 + sp)*64 + lane)*8];
                oacc[dt] = __builtin_amdgcn_mfma_f32_32x32x16_bf16(vf, pf.v, oacc[dt], 0, 0, 0);
            }
        }
    }

    // ---- epilogue: normalize, write bf16 O (8B packs of 4 consecutive d) ----
    float inv = 1.f / sum;
    ushort* op = obuf + ((size_t)(b*SEQ + qrow))*CH + hh*HD;
    #pragma unroll
    for (int dt = 0; dt < 2; ++dt)
        #pragma unroll
        for (int rg = 0; rg < 4; ++rg) {
            int d0 = dt*32 + rg*8 + hi*4;
            if (d0 < HD) {
                uint2 val;
                val.x = pk2(oacc[dt][rg*4+0]*inv, oacc[dt][rg*4+1]*inv);
                val.y = pk2(oacc[dt][rg*4+2]*inv, oacc[dt][rg*4+3]*inv);
                *(uint2*)(op + d0) = val;
            }
        }
}

// ---------------- launcher ----------------
extern "C" void kernel_launch(void* const* d_in, const int* in_sizes, int n_in,
                              void* d_out, int out_size, void* d_ws, size_t ws_size,
                              hipStream_t stream) {
    const float* x      = (const float*)d_in[0];
    const float* mask   = (const float*)d_in[1];
    const float* emb_w1 = (const float*)d_in[2];
    const float* emb_b1 = (const float*)d_in[3];
    const float* emb_w2 = (const float*)d_in[4];
    const float* emb_b2 = (const float*)d_in[5];
    const float* qkv_w  = (const float*)d_in[6];
    const float* proj_w = (const float*)d_in[7];
    const float* proj_b = (const float*)d_in[8];
    const float* mlp_w1 = (const float*)d_in[9];
    const float* mlp_b1 = (const float*)d_in[10];
    const float* mlp_w2 = (const float*)d_in[11];
    const float* mlp_b2 = (const float*)d_in[12];
    const float* ln1_s  = (const float*)d_in[13];
    const float* ln1_b  = (const float*)d_in[14];
    const float* ln2_s  = (const float*)d_in[15];
    const float* ln2_b  = (const float*)d_in[16];

    const size_t S1 = (size_t)NTOK*CH;
    float* ws   = (float*)d_ws;
    float*  h    = ws;                          // fp32 [NTOK][CH]
    float*  qkv  = h + S1;                      // fp32 [NTOK][C3]
    ushort* ybf  = (ushort*)(qkv + 3*S1);       // bf16 [NTOK][CH]
    ushort* t2bf = ybf  + S1;
    ushort* obf  = t2bf + S1;
    ushort* wb   = obf  + S1;
    ushort* wb_emb2 = wb;
    ushort* wb_qkv  = wb_emb2 + 147456;
    ushort* wb_proj = wb_qkv  + 2654208;
    ushort* wb_m1   = wb_proj + 884736;
    ushort* wb_m2   = wb_m1   + 884736;
    float*  tbl  = (float*)(wb_m2 + 884736);

    dim3 g6(3, 128);
    dim3 g18(9, 128);

    rope_table_kernel<<<1, 256, 0, stream>>>((float2*)tbl);
    f2bf4_kernel<<<144,  256, 0, stream>>>(emb_w2, wb_emb2);
    f2bf4_kernel<<<2592, 256, 0, stream>>>(qkv_w,  wb_qkv);
    f2bf4_kernel<<<864,  256, 0, stream>>>(proj_w, wb_proj);
    f2bf4_kernel<<<864,  256, 0, stream>>>(mlp_w1, wb_m1);
    f2bf4_kernel<<<864,  256, 0, stream>>>(mlp_w2, wb_m2);

    embed1_kernel<<<(NTOK*CH)/256, 256, 0, stream>>>(x, emb_w1, emb_b1, ybf);
    gemm_bf16_kernel<false,false><<<g6, 256, 0, stream>>>(ybf, CH, wb_emb2, CH,
            emb_b2, nullptr, h, CH, CH);

    for (int i = 0; i < DEPTH; ++i) {
        ln_kernel<<<NTOK/4, 256, 0, stream>>>(h, ln1_s + i*CH, ln1_b + i*CH, ybf);
        gemm_bf16_kernel<false,false><<<g18, 256, 0, stream>>>(ybf, CH,
                wb_qkv + (size_t)i*C3*CH, CH, nullptr, nullptr, qkv, C3, CH);
        attn_kernel<<<BATCH*NHEAD, 512, 0, stream>>>(qkv, mask, (const float2*)tbl, obf);
        gemm_bf16_kernel<false,false><<<g6, 256, 0, stream>>>(obf, CH,
                wb_proj + (size_t)i*CH*CH, CH, proj_b + i*CH, h, h, CH, CH);
        ln_kernel<<<NTOK/4, 256, 0, stream>>>(h, ln2_s + i*CH, ln2_b + i*CH, ybf);
        gemm_bf16_kernel<true,true><<<g6, 256, 0, stream>>>(ybf, CH,
                wb_m1 + (size_t)i*CH*CH, CH, mlp_b1 + i*CH, nullptr, t2bf, CH, CH);
        gemm_bf16_kernel<false,false><<<g6, 256, 0, stream>>>(t2bf, CH,
                wb_m2 + (size_t)i*CH*CH, CH, mlp_b2 + i*CH, h, h, CH, CH);
    }
    hipMemcpyAsync(d_out, h, S1*sizeof(float), hipMemcpyDeviceToDevice, stream);
}

// Round 5
// 1070.102 us; speedup vs baseline: 4.4148x; 1.2434x over previous
//
#include <hip/hip_runtime.h>
#include <hip/hip_bf16.h>
#include <math.h>

#define BATCH 64
#define SEQ   256
#define CH    384
#define NHEAD 8
#define HD    48
#define DEPTH 6
#define NTOK  (BATCH*SEQ)   // 16384
#define C3    (3*CH)        // 1152
#define LN_EPS 1e-5f
#define ATT_SCALE 0.14433756729740643f  // 48^-0.5

typedef __attribute__((ext_vector_type(8)))  short bf16x8;
typedef __attribute__((ext_vector_type(4)))  float f32x4;
typedef __attribute__((ext_vector_type(16))) float f32x16;

__device__ __forceinline__ ushort f2bf(float f) {
    __hip_bfloat16 h = __float2bfloat16(f);
    return *(ushort*)&h;
}
__device__ __forceinline__ float bfu2f(ushort u) {
    uint t = ((uint)u) << 16;
    union { uint u; float f; } c; c.u = t; return c.f;
}
__device__ __forceinline__ uint pk2(float a, float b) {
    return (uint)f2bf(a) | ((uint)f2bf(b) << 16);
}

#define AS1(p) ((const __attribute__((address_space(1))) void*)(p))
#define AS3(p) ((__attribute__((address_space(3))) void*)(uintptr_t)(p))

// ---------------- fp32 -> bf16 bulk convert ----------------
__global__ void f2bf4_kernel(const float* __restrict__ in, ushort* __restrict__ out) {
    int i = (blockIdx.x*256 + threadIdx.x)*4;
    float4 v = *(const float4*)(in + i);
    ushort4 o;
    o.x = f2bf(v.x); o.y = f2bf(v.y); o.z = f2bf(v.z); o.w = f2bf(v.w);
    *(ushort4*)(out + i) = o;
}

// ---------------- rope cos/sin table ----------------
__global__ void rope_table_kernel(float2* __restrict__ tbl) {
    int pos = threadIdx.x;
    for (int j = 0; j < 24; ++j) {
        float freq = exp2f(-(float)j * (13.287712379549449f / 24.0f));
        float ang = (float)pos * freq;
        float s, c;
        sincosf(ang, &s, &c);
        tbl[pos*24 + j] = make_float2(c, s);
    }
}

// ---------------- embed stage 1 -> bf16 ----------------
__global__ void embed1_kernel(const float* __restrict__ x, const float* __restrict__ w1,
                              const float* __restrict__ b1, ushort* __restrict__ out) {
    int idx = blockIdx.x*256 + threadIdx.x;
    int m = idx / CH, c = idx - m*CH;
    float v = x[m*2]*w1[c*2] + x[m*2+1]*w1[c*2+1] + b1[c];
    out[idx] = f2bf(fmaxf(v, 0.f));
}

// ---------------- LayerNorm fp32 -> bf16 ----------------
__global__ __launch_bounds__(256) void ln_kernel(const float* __restrict__ in,
        const float* __restrict__ gam, const float* __restrict__ bet,
        ushort* __restrict__ out) {
    int row  = blockIdx.x*4 + (threadIdx.x >> 6);
    int lane = threadIdx.x & 63;
    const float* p = in + (size_t)row*CH;
    float v[6];
    float sum = 0.f;
    #pragma unroll
    for (int i = 0; i < 6; ++i) { v[i] = p[lane + i*64]; sum += v[i]; }
    #pragma unroll
    for (int off = 1; off < 64; off <<= 1) sum += __shfl_xor(sum, off);
    float mu = sum * (1.0f/CH);
    float vs = 0.f;
    #pragma unroll
    for (int i = 0; i < 6; ++i) { float d = v[i]-mu; vs += d*d; }
    #pragma unroll
    for (int off = 1; off < 64; off <<= 1) vs += __shfl_xor(vs, off);
    float inv = rsqrtf(vs*(1.0f/CH) + LN_EPS);
    ushort* q = out + (size_t)row*CH;
    #pragma unroll
    for (int i = 0; i < 6; ++i) {
        int c = lane + i*64;
        q[c] = f2bf((v[i]-mu)*inv*gam[c] + bet[c]);
    }
}

// ---------------- bf16 MFMA NT-GEMM, 2-phase double-buffered, BN=128, BK=32 ----------------
// BM in {64,128}. Prefetch next K-tile into buf^1 before computing buf (T3-minimum).
template<int BM, bool RELU, bool BF16OUT>
__global__ __launch_bounds__(256) void gemm_bf16_kernel(
        const ushort* __restrict__ A, int lda,
        const ushort* __restrict__ W, int ldw,
        const float* __restrict__ bias,
        const float* __restrict__ resid,
        void* __restrict__ out, int ldo,
        int K) {
    constexpr int ACH = BM/16;        // A 1KB-chunks per K-step
    constexpr int NCH = ACH + 8;      // + B chunks (BN=128)
    constexpr int WM  = BM/32;        // M-frags per wave
    __shared__ __align__(16) ushort As[2][BM*32];
    __shared__ __align__(16) ushort Bs[2][128*32];
    const int tid  = threadIdx.x;
    const int lane = tid & 63;
    const int w    = tid >> 6;
    const int wr   = (w >> 1) * (BM/2);
    const int wc   = (w & 1) * 64;
    const int m0   = blockIdx.y * BM;
    const int n0   = blockIdx.x * 128;

    f32x4 acc[WM][4] = {};

    auto stage = [&](int pb, int k0) {
        #pragma unroll
        for (int c = 0; c < (NCH+3)/4; ++c) {
            int chunk = w + c*4;
            if (NCH & 3) { if (chunk >= NCH) break; }
            if (chunk < ACH) {
                int row = chunk*16 + (lane >> 2);
                const ushort* gp = A + (size_t)(m0+row)*lda + k0 + (lane & 3)*8;
                __builtin_amdgcn_global_load_lds(AS1(gp), AS3(&As[pb][chunk*512]), 16, 0, 0);
            } else {
                int row = (chunk-ACH)*16 + (lane >> 2);
                const ushort* gp = W + (size_t)(n0+row)*ldw + k0 + (lane & 3)*8;
                __builtin_amdgcn_global_load_lds(AS1(gp), AS3(&Bs[pb][(chunk-ACH)*512]), 16, 0, 0);
            }
        }
    };

    stage(0, 0);
    __syncthreads();          // drains prologue loads (vmcnt(0) implicit)
    int cur = 0;
    for (int k0 = 0; k0 < K; k0 += 32) {
        if (k0 + 32 < K) stage(cur^1, k0+32);   // prefetch next tile (in flight during compute)
        bf16x8 a[WM], b[4];
        #pragma unroll
        for (int i = 0; i < WM; ++i)
            a[i] = *(const bf16x8*)&As[cur][(wr + i*16 + (lane & 15))*32 + 8*(lane >> 4)];
        #pragma unroll
        for (int j = 0; j < 4; ++j)
            b[j] = *(const bf16x8*)&Bs[cur][(wc + j*16 + (lane & 15))*32 + 8*(lane >> 4)];
        #pragma unroll
        for (int i = 0; i < WM; ++i)
            #pragma unroll
            for (int j = 0; j < 4; ++j)
                acc[i][j] = __builtin_amdgcn_mfma_f32_16x16x32_bf16(a[i], b[j], acc[i][j], 0, 0, 0);
        __syncthreads();      // reads done + prefetch drained -> safe to swap
        cur ^= 1;
    }

    const int cbase = n0 + wc + (lane & 15);
    const int rbase = m0 + wr + ((lane >> 4) << 2);
    #pragma unroll
    for (int i = 0; i < WM; ++i)
        #pragma unroll
        for (int r = 0; r < 4; ++r) {
            int m = rbase + i*16 + r;
            #pragma unroll
            for (int j = 0; j < 4; ++j) {
                int n = cbase + j*16;
                float v = acc[i][j][r];
                if (bias)  v += bias[n];
                if (RELU)  v = fmaxf(v, 0.f);
                if (resid) v += resid[(size_t)m*ldo + n];
                if (BF16OUT) ((ushort*)out)[(size_t)m*ldo + n] = f2bf(v);
                else         ((float*)out)[(size_t)m*ldo + n]  = v;
            }
        }
}

// ---------------- MFMA attention (bf16 qkv input): block=(b,h), 8 waves, wave=32 q-rows ----------------
__global__ __launch_bounds__(512) void attn_kernel(
        const ushort* __restrict__ qkv, const float* __restrict__ mask,
        const float2* __restrict__ tbl, ushort* __restrict__ obuf) {
    __shared__ __align__(16) ushort Kf[8*3*64*8];   // 24 KB
    __shared__ __align__(16) ushort Vf[2*16*64*8];  // 32 KB
    __shared__ float Ms[SEQ];

    const int bid = blockIdx.x;
    const int b   = bid >> 3;
    const int hh  = bid & 7;
    const int tid = threadIdx.x;
    const int lane = tid & 63;
    const int hi   = (lane >> 5);
    const int q5   = lane & 31;
    const ushort* base = qkv + (size_t)b*SEQ*C3;

    // ---- stage K as QK A-fragments, rope fused ----
    {
        int t   = tid >> 6;
        int row = t*32 + q5;
        const ushort* kp = base + (size_t)row*C3 + CH + hh*HD;
        #pragma unroll
        for (int s = 0; s < 3; ++s) {
            union { ushort us[8]; bf16x8 v; } raw;
            raw.v = *(const bf16x8*)(kp + s*16 + hi*8);
            union { uint w[4]; bf16x8 v; } u;
            #pragma unroll
            for (int p = 0; p < 4; ++p) {
                float2 cs = tbl[row*24 + s*8 + hi*4 + p];
                float xu = bfu2f(raw.us[2*p]), xe = bfu2f(raw.us[2*p+1]);
                u.w[p] = pk2(xu*cs.x - xe*cs.y, xu*cs.y + xe*cs.x);
            }
            *(bf16x8*)&Kf[((t*3 + s)*64 + lane)*8] = u.v;
        }
    }
    // ---- stage V^T as PV A-fragments (d = dt*32 + q5, zero-pad d>=48) ----
    {
        #pragma unroll
        for (int p = 0; p < 4; ++p) {
            int dt = p >> 1;
            int sp = (tid >> 6)*2 + (p & 1);
            int dd = dt*32 + q5;
            union { uint w[4]; bf16x8 v; } u;
            if (dd < HD) {
                const ushort* vp = base + (size_t)(sp*16 + hi*8)*C3 + 2*CH + hh*HD + dd;
                #pragma unroll
                for (int k = 0; k < 4; ++k)
                    u.w[k] = (uint)vp[(2*k)*C3] | ((uint)vp[(2*k+1)*C3] << 16);
            } else {
                u.w[0] = u.w[1] = u.w[2] = u.w[3] = 0u;
            }
            *(bf16x8*)&Vf[((dt*16 + sp)*64 + lane)*8] = u.v;
        }
    }
    if (tid < SEQ) Ms[tid] = mask[b*SEQ + tid];

    // ---- per-wave Q B-fragments (rope + scale fused) ----
    const int wv    = tid >> 6;
    const int qrow  = wv*32 + q5;
    bf16x8 qf[3];
    {
        const ushort* qp = base + (size_t)qrow*C3 + hh*HD;
        #pragma unroll
        for (int s = 0; s < 3; ++s) {
            union { ushort us[8]; bf16x8 v; } raw;
            raw.v = *(const bf16x8*)(qp + s*16 + hi*8);
            union { uint w[4]; bf16x8 v; } u;
            #pragma unroll
            for (int p = 0; p < 4; ++p) {
                float2 cs = tbl[qrow*24 + s*8 + hi*4 + p];
                float xu = bfu2f(raw.us[2*p]), xe = bfu2f(raw.us[2*p+1]);
                u.w[p] = pk2((xu*cs.x - xe*cs.y)*ATT_SCALE, (xu*cs.y + xe*cs.x)*ATT_SCALE);
            }
            qf[s] = u.v;
        }
    }
    __syncthreads();

    // ---- S^T = mfma(K, Q): 8 k-tiles x 3 d-steps ----
    f32x16 st[8] = {};
    #pragma unroll
    for (int t = 0; t < 8; ++t)
        #pragma unroll
        for (int s = 0; s < 3; ++s) {
            bf16x8 af = *(const bf16x8*)&Kf[((t*3 + s)*64 + lane)*8];
            st[t] = __builtin_amdgcn_mfma_f32_32x32x16_bf16(af, qf[s], st[t], 0, 0, 0);
        }

    // ---- register softmax ----
    float mx = -1e30f;
    #pragma unroll
    for (int t = 0; t < 8; ++t)
        #pragma unroll
        for (int r = 0; r < 16; ++r) {
            int kt = t*32 + (r & 3) + 8*(r >> 2) + 4*hi;
            float s = st[t][r] + Ms[kt];
            st[t][r] = s;
            mx = fmaxf(mx, s);
        }
    mx = fmaxf(mx, __shfl_xor(mx, 32));
    float sum = 0.f;
    #pragma unroll
    for (int t = 0; t < 8; ++t)
        #pragma unroll
        for (int r = 0; r < 16; ++r) {
            float p = __expf(st[t][r] - mx);
            st[t][r] = p;
            sum += p;
        }
    sum += __shfl_xor(sum, 32);

    // ---- PV: O^T += V^T . P^T ----
    f32x16 oacc[2] = {};
    #pragma unroll
    for (int t = 0; t < 8; ++t) {
        uint w[4][2];
        #pragma unroll
        for (int g = 0; g < 4; ++g) {
            w[g][0] = pk2(st[t][g*4+0], st[t][g*4+1]);
            w[g][1] = pk2(st[t][g*4+2], st[t][g*4+3]);
        }
        #pragma unroll
        for (int o = 0; o < 2; ++o) {
            uint x0 = __shfl_xor(hi ? w[2*o][0] : w[2*o+1][0], 32);
            uint x1 = __shfl_xor(hi ? w[2*o][1] : w[2*o+1][1], 32);
            union { uint w[4]; bf16x8 v; } pf;
            if (hi == 0) { pf.w[0] = w[2*o][0]; pf.w[1] = w[2*o][1]; pf.w[2] = x0; pf.w[3] = x1; }
            else         { pf.w[0] = x0; pf.w[1] = x1; pf.w[2] = w[2*o+1][0]; pf.w[3] = w[2*o+1][1]; }
            int sp = t*2 + o;
            #pragma unroll
            for (int dt = 0; dt < 2; ++dt) {
                bf16x8 vf = *(const bf16x8*)&Vf[((dt*16 + sp)*64 + lane)*8];
                oacc[dt] = __builtin_amdgcn_mfma_f32_32x32x16_bf16(vf, pf.v, oacc[dt], 0, 0, 0);
            }
        }
    }

    float inv = 1.f / sum;
    ushort* op = obuf + ((size_t)(b*SEQ + qrow))*CH + hh*HD;
    #pragma unroll
    for (int dt = 0; dt < 2; ++dt)
        #pragma unroll
        for (int rg = 0; rg < 4; ++rg) {
            int d0 = dt*32 + rg*8 + hi*4;
            if (d0 < HD) {
                uint2 val;
                val.x = pk2(oacc[dt][rg*4+0]*inv, oacc[dt][rg*4+1]*inv);
                val.y = pk2(oacc[dt][rg*4+2]*inv, oacc[dt][rg*4+3]*inv);
                *(uint2*)(op + d0) = val;
            }
        }
}

// ---------------- launcher ----------------
extern "C" void kernel_launch(void* const* d_in, const int* in_sizes, int n_in,
                              void* d_out, int out_size, void* d_ws, size_t ws_size,
                              hipStream_t stream) {
    const float* x      = (const float*)d_in[0];
    const float* mask   = (const float*)d_in[1];
    const float* emb_w1 = (const float*)d_in[2];
    const float* emb_b1 = (const float*)d_in[3];
    const float* emb_w2 = (const float*)d_in[4];
    const float* emb_b2 = (const float*)d_in[5];
    const float* qkv_w  = (const float*)d_in[6];
    const float* proj_w = (const float*)d_in[7];
    const float* proj_b = (const float*)d_in[8];
    const float* mlp_w1 = (const float*)d_in[9];
    const float* mlp_b1 = (const float*)d_in[10];
    const float* mlp_w2 = (const float*)d_in[11];
    const float* mlp_b2 = (const float*)d_in[12];
    const float* ln1_s  = (const float*)d_in[13];
    const float* ln1_b  = (const float*)d_in[14];
    const float* ln2_s  = (const float*)d_in[15];
    const float* ln2_b  = (const float*)d_in[16];

    const size_t S1 = (size_t)NTOK*CH;
    float*  h     = (float*)d_ws;               // fp32 [NTOK][CH]
    ushort* qkvbf = (ushort*)(h + S1);          // bf16 [NTOK][C3]
    ushort* ybf   = qkvbf + 3*S1;               // bf16 [NTOK][CH]
    ushort* t2bf  = ybf  + S1;
    ushort* obf   = t2bf + S1;
    ushort* wb_emb2 = obf + S1;
    ushort* wb_qkv  = wb_emb2 + 147456;
    ushort* wb_proj = wb_qkv  + 2654208;
    ushort* wb_m1   = wb_proj + 884736;
    ushort* wb_m2   = wb_m1   + 884736;
    float*  tbl  = (float*)(wb_m2 + 884736);

    dim3 g64n384(3, 256);    // BM=64 tiles: N=384
    dim3 g128qkv(9, 128);    // BM=128: N=1152

    rope_table_kernel<<<1, 256, 0, stream>>>((float2*)tbl);
    f2bf4_kernel<<<144,  256, 0, stream>>>(emb_w2, wb_emb2);
    f2bf4_kernel<<<2592, 256, 0, stream>>>(qkv_w,  wb_qkv);
    f2bf4_kernel<<<864,  256, 0, stream>>>(proj_w, wb_proj);
    f2bf4_kernel<<<864,  256, 0, stream>>>(mlp_w1, wb_m1);
    f2bf4_kernel<<<864,  256, 0, stream>>>(mlp_w2, wb_m2);

    embed1_kernel<<<(NTOK*CH)/256, 256, 0, stream>>>(x, emb_w1, emb_b1, ybf);
    gemm_bf16_kernel<64,false,false><<<g64n384, 256, 0, stream>>>(ybf, CH, wb_emb2, CH,
            emb_b2, nullptr, h, CH, CH);

    for (int i = 0; i < DEPTH; ++i) {
        ln_kernel<<<NTOK/4, 256, 0, stream>>>(h, ln1_s + i*CH, ln1_b + i*CH, ybf);
        gemm_bf16_kernel<128,false,true><<<g128qkv, 256, 0, stream>>>(ybf, CH,
                wb_qkv + (size_t)i*C3*CH, CH, nullptr, nullptr, qkvbf, C3, CH);
        attn_kernel<<<BATCH*NHEAD, 512, 0, stream>>>(qkvbf, mask, (const float2*)tbl, obf);
        gemm_bf16_kernel<64,false,false><<<g64n384, 256, 0, stream>>>(obf, CH,
                wb_proj + (size_t)i*CH*CH, CH, proj_b + i*CH, h, h, CH, CH);
        ln_kernel<<<NTOK/4, 256, 0, stream>>>(h, ln2_s + i*CH, ln2_b + i*CH, ybf);
        gemm_bf16_kernel<64,true,true><<<g64n384, 256, 0, stream>>>(ybf, CH,
                wb_m1 + (size_t)i*CH*CH, CH, mlp_b1 + i*CH, nullptr, t2bf, CH, CH);
        gemm_bf16_kernel<64,false,false><<<g64n384, 256, 0, stream>>>(t2bf, CH,
                wb_m2 + (size_t)i*CH*CH, CH, mlp_b2 + i*CH, h, h, CH, CH);
    }
    hipMemcpyAsync(d_out, h, S1*sizeof(float), hipMemcpyDeviceToDevice, stream);
}

// Round 6
// 1021.810 us; speedup vs baseline: 4.6235x; 1.0473x over previous
//
#include <hip/hip_runtime.h>
#include <hip/hip_bf16.h>
#include <math.h>

#define BATCH 64
#define SEQ   256
#define CH    384
#define NHEAD 8
#define HD    48
#define DEPTH 6
#define NTOK  (BATCH*SEQ)   // 16384
#define C3    (3*CH)        // 1152
#define LN_EPS 1e-5f
#define ATT_SCALE 0.14433756729740643f  // 48^-0.5

typedef __attribute__((ext_vector_type(8)))  short bf16x8;
typedef __attribute__((ext_vector_type(4)))  float f32x4;
typedef __attribute__((ext_vector_type(16))) float f32x16;

__device__ __forceinline__ ushort f2bf(float f) {
    __hip_bfloat16 h = __float2bfloat16(f);
    return *(ushort*)&h;
}
__device__ __forceinline__ float bfu2f(ushort u) {
    uint t = ((uint)u) << 16;
    union { uint u; float f; } c; c.u = t; return c.f;
}
__device__ __forceinline__ uint pk2(float a, float b) {
    return (uint)f2bf(a) | ((uint)f2bf(b) << 16);
}

#define AS1(p) ((const __attribute__((address_space(1))) void*)(p))
#define AS3(p) ((__attribute__((address_space(3))) void*)(uintptr_t)(p))
#define WAITVMC(N) asm volatile("s_waitcnt vmcnt(" #N ")" ::: "memory")
#define TAILSYNC() do { \
    asm volatile("s_waitcnt lgkmcnt(0)" ::: "memory"); \
    __builtin_amdgcn_sched_barrier(0); \
    __builtin_amdgcn_s_barrier(); } while (0)

// ---------------- fp32 -> bf16 bulk convert ----------------
__global__ void f2bf4_kernel(const float* __restrict__ in, ushort* __restrict__ out) {
    int i = (blockIdx.x*256 + threadIdx.x)*4;
    float4 v = *(const float4*)(in + i);
    ushort4 o;
    o.x = f2bf(v.x); o.y = f2bf(v.y); o.z = f2bf(v.z); o.w = f2bf(v.w);
    *(ushort4*)(out + i) = o;
}

// ---------------- rope cos/sin table ----------------
__global__ void rope_table_kernel(float2* __restrict__ tbl) {
    int pos = threadIdx.x;
    for (int j = 0; j < 24; ++j) {
        float freq = exp2f(-(float)j * (13.287712379549449f / 24.0f));
        float ang = (float)pos * freq;
        float s, c;
        sincosf(ang, &s, &c);
        tbl[pos*24 + j] = make_float2(c, s);
    }
}

// ---------------- embed stage 1 -> bf16 ----------------
__global__ void embed1_kernel(const float* __restrict__ x, const float* __restrict__ w1,
                              const float* __restrict__ b1, ushort* __restrict__ out) {
    int idx = blockIdx.x*256 + threadIdx.x;
    int m = idx / CH, c = idx - m*CH;
    float v = x[m*2]*w1[c*2] + x[m*2+1]*w1[c*2+1] + b1[c];
    out[idx] = f2bf(fmaxf(v, 0.f));
}

// ---------------- qkv GEMM: BM=128, BN=128, K=384, ring-3 counted-vmcnt ----------------
__global__ __launch_bounds__(256) void gemm_qkv_kernel(
        const ushort* __restrict__ A,   // [M][384] bf16
        const ushort* __restrict__ W,   // [1152][384] bf16
        ushort* __restrict__ out) {     // [M][1152] bf16
    __shared__ __align__(16) ushort As[3][128*32];
    __shared__ __align__(16) ushort Bs[3][128*32];
    const int tid  = threadIdx.x;
    const int lane = tid & 63;
    const int w    = tid >> 6;
    const int wr   = (w >> 1) * 64;
    const int wc   = (w & 1) * 64;
    const int m0   = blockIdx.y * 128;
    const int n0   = blockIdx.x * 128;

    f32x4 acc[4][4] = {};

    auto stage = [&](int pb, int t) {
        int k0 = t*32;
        #pragma unroll
        for (int c = 0; c < 4; ++c) {
            int chunk = w + c*4;   // 4 loads/wave
            if (chunk < 8) {
                int row = chunk*16 + (lane >> 2);
                const ushort* gp = A + (size_t)(m0+row)*CH + k0 + (lane & 3)*8;
                __builtin_amdgcn_global_load_lds(AS1(gp), AS3(&As[pb][chunk*512]), 16, 0, 0);
            } else {
                int row = (chunk-8)*16 + (lane >> 2);
                const ushort* gp = W + (size_t)(n0+row)*CH + k0 + (lane & 3)*8;
                __builtin_amdgcn_global_load_lds(AS1(gp), AS3(&Bs[pb][(chunk-8)*512]), 16, 0, 0);
            }
        }
    };

    stage(0, 0); stage(1, 1);
    for (int t = 0; t < 12; ++t) {
        if (t < 11) { WAITVMC(4); } else { WAITVMC(0); }   // tile t complete (own wave)
        __builtin_amdgcn_s_barrier();                       // all waves' tile-t loads done
        if (t + 2 < 12) stage((t+2)%3, t+2);                // depth-2 prefetch
        const int pb = t % 3;
        bf16x8 a[4], b[4];
        #pragma unroll
        for (int i = 0; i < 4; ++i)
            a[i] = *(const bf16x8*)&As[pb][(wr + i*16 + (lane & 15))*32 + 8*(lane >> 4)];
        #pragma unroll
        for (int j = 0; j < 4; ++j)
            b[j] = *(const bf16x8*)&Bs[pb][(wc + j*16 + (lane & 15))*32 + 8*(lane >> 4)];
        #pragma unroll
        for (int i = 0; i < 4; ++i)
            #pragma unroll
            for (int j = 0; j < 4; ++j)
                acc[i][j] = __builtin_amdgcn_mfma_f32_16x16x32_bf16(a[i], b[j], acc[i][j], 0, 0, 0);
        TAILSYNC();   // reads retired before buffer reuse next iteration
    }

    const int cbase = n0 + wc + (lane & 15);
    const int rbase = m0 + wr + ((lane >> 4) << 2);
    #pragma unroll
    for (int i = 0; i < 4; ++i)
        #pragma unroll
        for (int r = 0; r < 4; ++r) {
            int m = rbase + i*16 + r;
            #pragma unroll
            for (int j = 0; j < 4; ++j)
                out[(size_t)m*C3 + cbase + j*16] = f2bf(acc[i][j][r]);
        }
}

// ---------------- fused N=384 GEMM (+bias,[relu],[resid]) -> h fp32 + [LN] bf16 ----------------
// BM=64, BN=384 (full row per block), K=384, ring-3 counted-vmcnt. Grid: 256 blocks.
template<bool RELU, bool RESID>
__global__ __launch_bounds__(256) void fgemm_kernel(
        const ushort* __restrict__ A,      // [M][384] bf16
        const ushort* __restrict__ W,      // [384][384] bf16
        const float* __restrict__ bias,    // [384]
        const float* __restrict__ resid,   // [M][384] fp32 (RESID)
        float* __restrict__ hout,          // [M][384] fp32 or null
        const float* __restrict__ gam, const float* __restrict__ bet,
        int doLN,
        ushort* __restrict__ ybf) {        // [M][384] bf16 or null
    __shared__ __align__(16) ushort As[3][64*32];    // 12 KB
    __shared__ __align__(16) ushort Bs[3][384*32];   // 72 KB
    __shared__ float Red1[64][2], Red2[64][2];
    const int tid  = threadIdx.x;
    const int lane = tid & 63;
    const int w    = tid >> 6;
    const int l15  = lane & 15;
    const int g    = lane >> 4;
    const int wr   = (w & 1) * 32;     // row half
    const int wh   = (w >> 1);         // col half 0/1
    const int wc   = wh * 192;
    const int m0   = blockIdx.x * 64;

    f32x4 acc[2][12] = {};

    auto stage = [&](int pb, int t) {
        int k0 = t*32;
        #pragma unroll
        for (int c = 0; c < 7; ++c) {
            int chunk = w + c*4;   // 7 loads/wave, 28 chunks
            if (chunk < 4) {
                int row = chunk*16 + (lane >> 2);
                const ushort* gp = A + (size_t)(m0+row)*CH + k0 + (lane & 3)*8;
                __builtin_amdgcn_global_load_lds(AS1(gp), AS3(&As[pb][chunk*512]), 16, 0, 0);
            } else {
                int row = (chunk-4)*16 + (lane >> 2);
                const ushort* gp = W + (size_t)row*CH + k0 + (lane & 3)*8;
                __builtin_amdgcn_global_load_lds(AS1(gp), AS3(&Bs[pb][(chunk-4)*512]), 16, 0, 0);
            }
        }
    };

    stage(0, 0); stage(1, 1);
    for (int t = 0; t < 12; ++t) {
        if (t < 11) { WAITVMC(7); } else { WAITVMC(0); }
        __builtin_amdgcn_s_barrier();
        if (t + 2 < 12) stage((t+2)%3, t+2);
        const int pb = t % 3;
        bf16x8 a[2], b[12];
        #pragma unroll
        for (int i = 0; i < 2; ++i)
            a[i] = *(const bf16x8*)&As[pb][(wr + i*16 + l15)*32 + 8*g];
        #pragma unroll
        for (int j = 0; j < 12; ++j)
            b[j] = *(const bf16x8*)&Bs[pb][(wc + j*16 + l15)*32 + 8*g];
        #pragma unroll
        for (int i = 0; i < 2; ++i)
            #pragma unroll
            for (int j = 0; j < 12; ++j)
                acc[i][j] = __builtin_amdgcn_mfma_f32_16x16x32_bf16(a[i], b[j], acc[i][j], 0, 0, 0);
        TAILSYNC();
    }

    // ---- epilogue: bias/relu/resid in-place ----
    #pragma unroll
    for (int i = 0; i < 2; ++i)
        #pragma unroll
        for (int j = 0; j < 12; ++j) {
            int n = wc + j*16 + l15;
            float bv = bias[n];
            #pragma unroll
            for (int r = 0; r < 4; ++r) {
                float v = acc[i][j][r] + bv;
                if (RELU)  v = fmaxf(v, 0.f);
                if (RESID) v += resid[(size_t)(m0 + wr + i*16 + g*4 + r)*CH + n];
                acc[i][j][r] = v;
            }
        }

    // ---- block-wide two-pass LN stats (rows = wr+i*16+g*4+r; cols split across wh) ----
    float mu[2][4]  = {{0.f,0.f,0.f,0.f},{0.f,0.f,0.f,0.f}};
    float inv[2][4] = {{1.f,1.f,1.f,1.f},{1.f,1.f,1.f,1.f}};
    if (doLN) {
        #pragma unroll
        for (int i = 0; i < 2; ++i)
            #pragma unroll
            for (int r = 0; r < 4; ++r) {
                float s = 0.f;
                #pragma unroll
                for (int j = 0; j < 12; ++j) s += acc[i][j][r];
                #pragma unroll
                for (int off = 1; off < 16; off <<= 1) s += __shfl_xor(s, off);
                if (l15 == 0) Red1[wr + i*16 + g*4 + r][wh] = s;
            }
        __syncthreads();
        #pragma unroll
        for (int i = 0; i < 2; ++i)
            #pragma unroll
            for (int r = 0; r < 4; ++r) {
                int rowb = wr + i*16 + g*4 + r;
                mu[i][r] = (Red1[rowb][0] + Red1[rowb][1]) * (1.0f/CH);
                float s = 0.f;
                #pragma unroll
                for (int j = 0; j < 12; ++j) {
                    float d = acc[i][j][r] - mu[i][r];
                    s += d*d;
                }
                #pragma unroll
                for (int off = 1; off < 16; off <<= 1) s += __shfl_xor(s, off);
                if (l15 == 0) Red2[rowb][wh] = s;
            }
        __syncthreads();
        #pragma unroll
        for (int i = 0; i < 2; ++i)
            #pragma unroll
            for (int r = 0; r < 4; ++r) {
                int rowb = wr + i*16 + g*4 + r;
                float var = (Red2[rowb][0] + Red2[rowb][1]) * (1.0f/CH);
                inv[i][r] = rsqrtf(var + LN_EPS);
            }
    }

    // ---- writes ----
    #pragma unroll
    for (int i = 0; i < 2; ++i)
        #pragma unroll
        for (int r = 0; r < 4; ++r) {
            int m = m0 + wr + i*16 + g*4 + r;
            #pragma unroll
            for (int j = 0; j < 12; ++j) {
                int n = wc + j*16 + l15;
                float v = acc[i][j][r];
                if (hout) hout[(size_t)m*CH + n] = v;
                if (ybf) {
                    float yv = doLN ? (v - mu[i][r])*inv[i][r]*gam[n] + bet[n] : v;
                    ybf[(size_t)m*CH + n] = f2bf(yv);
                }
            }
        }
}

// ---------------- MFMA attention (bf16 qkv input): block=(b,h), 8 waves, wave=32 q-rows ----------------
__global__ __launch_bounds__(512) void attn_kernel(
        const ushort* __restrict__ qkv, const float* __restrict__ mask,
        const float2* __restrict__ tbl, ushort* __restrict__ obuf) {
    __shared__ __align__(16) ushort Kf[8*3*64*8];   // 24 KB
    __shared__ __align__(16) ushort Vf[2*16*64*8];  // 32 KB
    __shared__ float Ms[SEQ];

    const int bid = blockIdx.x;
    const int b   = bid >> 3;
    const int hh  = bid & 7;
    const int tid = threadIdx.x;
    const int lane = tid & 63;
    const int hi   = (lane >> 5);
    const int q5   = lane & 31;
    const ushort* base = qkv + (size_t)b*SEQ*C3;

    {
        int t   = tid >> 6;
        int row = t*32 + q5;
        const ushort* kp = base + (size_t)row*C3 + CH + hh*HD;
        #pragma unroll
        for (int s = 0; s < 3; ++s) {
            union { ushort us[8]; bf16x8 v; } raw;
            raw.v = *(const bf16x8*)(kp + s*16 + hi*8);
            union { uint w[4]; bf16x8 v; } u;
            #pragma unroll
            for (int p = 0; p < 4; ++p) {
                float2 cs = tbl[row*24 + s*8 + hi*4 + p];
                float xu = bfu2f(raw.us[2*p]), xe = bfu2f(raw.us[2*p+1]);
                u.w[p] = pk2(xu*cs.x - xe*cs.y, xu*cs.y + xe*cs.x);
            }
            *(bf16x8*)&Kf[((t*3 + s)*64 + lane)*8] = u.v;
        }
    }
    {
        #pragma unroll
        for (int p = 0; p < 4; ++p) {
            int dt = p >> 1;
            int sp = (tid >> 6)*2 + (p & 1);
            int dd = dt*32 + q5;
            union { uint w[4]; bf16x8 v; } u;
            if (dd < HD) {
                const ushort* vp = base + (size_t)(sp*16 + hi*8)*C3 + 2*CH + hh*HD + dd;
                #pragma unroll
                for (int k = 0; k < 4; ++k)
                    u.w[k] = (uint)vp[(2*k)*C3] | ((uint)vp[(2*k+1)*C3] << 16);
            } else {
                u.w[0] = u.w[1] = u.w[2] = u.w[3] = 0u;
            }
            *(bf16x8*)&Vf[((dt*16 + sp)*64 + lane)*8] = u.v;
        }
    }
    if (tid < SEQ) Ms[tid] = mask[b*SEQ + tid];

    const int wv    = tid >> 6;
    const int qrow  = wv*32 + q5;
    bf16x8 qf[3];
    {
        const ushort* qp = base + (size_t)qrow*C3 + hh*HD;
        #pragma unroll
        for (int s = 0; s < 3; ++s) {
            union { ushort us[8]; bf16x8 v; } raw;
            raw.v = *(const bf16x8*)(qp + s*16 + hi*8);
            union { uint w[4]; bf16x8 v; } u;
            #pragma unroll
            for (int p = 0; p < 4; ++p) {
                float2 cs = tbl[qrow*24 + s*8 + hi*4 + p];
                float xu = bfu2f(raw.us[2*p]), xe = bfu2f(raw.us[2*p+1]);
                u.w[p] = pk2((xu*cs.x - xe*cs.y)*ATT_SCALE, (xu*cs.y + xe*cs.x)*ATT_SCALE);
            }
            qf[s] = u.v;
        }
    }
    __syncthreads();

    f32x16 st[8] = {};
    #pragma unroll
    for (int t = 0; t < 8; ++t)
        #pragma unroll
        for (int s = 0; s < 3; ++s) {
            bf16x8 af = *(const bf16x8*)&Kf[((t*3 + s)*64 + lane)*8];
            st[t] = __builtin_amdgcn_mfma_f32_32x32x16_bf16(af, qf[s], st[t], 0, 0, 0);
        }

    float mx = -1e30f;
    #pragma unroll
    for (int t = 0; t < 8; ++t)
        #pragma unroll
        for (int r = 0; r < 16; ++r) {
            int kt = t*32 + (r & 3) + 8*(r >> 2) + 4*hi;
            float s = st[t][r] + Ms[kt];
            st[t][r] = s;
            mx = fmaxf(mx, s);
        }
    mx = fmaxf(mx, __shfl_xor(mx, 32));
    float sum = 0.f;
    #pragma unroll
    for (int t = 0; t < 8; ++t)
        #pragma unroll
        for (int r = 0; r < 16; ++r) {
            float p = __expf(st[t][r] - mx);
            st[t][r] = p;
            sum += p;
        }
    sum += __shfl_xor(sum, 32);

    f32x16 oacc[2] = {};
    #pragma unroll
    for (int t = 0; t < 8; ++t) {
        uint w[4][2];
        #pragma unroll
        for (int g = 0; g < 4; ++g) {
            w[g][0] = pk2(st[t][g*4+0], st[t][g*4+1]);
            w[g][1] = pk2(st[t][g*4+2], st[t][g*4+3]);
        }
        #pragma unroll
        for (int o = 0; o < 2; ++o) {
            uint x0 = __shfl_xor(hi ? w[2*o][0] : w[2*o+1][0], 32);
            uint x1 = __shfl_xor(hi ? w[2*o][1] : w[2*o+1][1], 32);
            union { uint w[4]; bf16x8 v; } pf;
            if (hi == 0) { pf.w[0] = w[2*o][0]; pf.w[1] = w[2*o][1]; pf.w[2] = x0; pf.w[3] = x1; }
            else         { pf.w[0] = x0; pf.w[1] = x1; pf.w[2] = w[2*o+1][0]; pf.w[3] = w[2*o+1][1]; }
            int sp = t*2 + o;
            #pragma unroll
            for (int dt = 0; dt < 2; ++dt) {
                bf16x8 vf = *(const bf16x8*)&Vf[((dt*16 + sp)*64 + lane)*8];
                oacc[dt] = __builtin_amdgcn_mfma_f32_32x32x16_bf16(vf, pf.v, oacc[dt], 0, 0, 0);
            }
        }
    }

    float inv = 1.f / sum;
    ushort* op = obuf + ((size_t)(b*SEQ + qrow))*CH + hh*HD;
    #pragma unroll
    for (int dt = 0; dt < 2; ++dt)
        #pragma unroll
        for (int rg = 0; rg < 4; ++rg) {
            int d0 = dt*32 + rg*8 + hi*4;
            if (d0 < HD) {
                uint2 val;
                val.x = pk2(oacc[dt][rg*4+0]*inv, oacc[dt][rg*4+1]*inv);
                val.y = pk2(oacc[dt][rg*4+2]*inv, oacc[dt][rg*4+3]*inv);
                *(uint2*)(op + d0) = val;
            }
        }
}

// ---------------- launcher ----------------
extern "C" void kernel_launch(void* const* d_in, const int* in_sizes, int n_in,
                              void* d_out, int out_size, void* d_ws, size_t ws_size,
                              hipStream_t stream) {
    const float* x      = (const float*)d_in[0];
    const float* mask   = (const float*)d_in[1];
    const float* emb_w1 = (const float*)d_in[2];
    const float* emb_b1 = (const float*)d_in[3];
    const float* emb_w2 = (const float*)d_in[4];
    const float* emb_b2 = (const float*)d_in[5];
    const float* qkv_w  = (const float*)d_in[6];
    const float* proj_w = (const float*)d_in[7];
    const float* proj_b = (const float*)d_in[8];
    const float* mlp_w1 = (const float*)d_in[9];
    const float* mlp_b1 = (const float*)d_in[10];
    const float* mlp_w2 = (const float*)d_in[11];
    const float* mlp_b2 = (const float*)d_in[12];
    const float* ln1_s  = (const float*)d_in[13];
    const float* ln1_b  = (const float*)d_in[14];
    const float* ln2_s  = (const float*)d_in[15];
    const float* ln2_b  = (const float*)d_in[16];

    const size_t S1 = (size_t)NTOK*CH;
    float*  h     = (float*)d_ws;               // fp32 [NTOK][CH]
    ushort* qkvbf = (ushort*)(h + S1);          // bf16 [NTOK][C3]
    ushort* ybf   = qkvbf + 3*S1;               // bf16 [NTOK][CH]
    ushort* t2bf  = ybf  + S1;
    ushort* obf   = t2bf + S1;
    ushort* wb_emb2 = obf + S1;
    ushort* wb_qkv  = wb_emb2 + 147456;
    ushort* wb_proj = wb_qkv  + 2654208;
    ushort* wb_m1   = wb_proj + 884736;
    ushort* wb_m2   = wb_m1   + 884736;
    float*  tbl  = (float*)(wb_m2 + 884736);

    dim3 gqkv(9, 128);       // BN=128 x BM=128
    const int gf = NTOK/64;  // 256 blocks for fused N=384 GEMMs

    rope_table_kernel<<<1, 256, 0, stream>>>((float2*)tbl);
    f2bf4_kernel<<<144,  256, 0, stream>>>(emb_w2, wb_emb2);
    f2bf4_kernel<<<2592, 256, 0, stream>>>(qkv_w,  wb_qkv);
    f2bf4_kernel<<<864,  256, 0, stream>>>(proj_w, wb_proj);
    f2bf4_kernel<<<864,  256, 0, stream>>>(mlp_w1, wb_m1);
    f2bf4_kernel<<<864,  256, 0, stream>>>(mlp_w2, wb_m2);

    embed1_kernel<<<(NTOK*CH)/256, 256, 0, stream>>>(x, emb_w1, emb_b1, ybf);
    // embed2 + LN1(0): h = y@emb_w2^T + b2 ; ybf = LN1_0(h)   (in-place A=ybf safe)
    fgemm_kernel<false,false><<<gf, 256, 0, stream>>>(ybf, wb_emb2, emb_b2,
            nullptr, h, ln1_s, ln1_b, 1, ybf);

    for (int i = 0; i < DEPTH; ++i) {
        gemm_qkv_kernel<<<gqkv, 256, 0, stream>>>(ybf, wb_qkv + (size_t)i*C3*CH, qkvbf);
        attn_kernel<<<BATCH*NHEAD, 512, 0, stream>>>(qkvbf, mask, (const float2*)tbl, obf);
        // proj + resid + LN2: h += proj(o)+b ; ybf = LN2(h)
        fgemm_kernel<false,true><<<gf, 256, 0, stream>>>(obf, wb_proj + (size_t)i*CH*CH,
                proj_b + i*CH, h, h, ln2_s + i*CH, ln2_b + i*CH, 1, ybf);
        // mlp1: t2 = relu(y@W1^T + b1)
        fgemm_kernel<true,false><<<gf, 256, 0, stream>>>(ybf, wb_m1 + (size_t)i*CH*CH,
                mlp_b1 + i*CH, nullptr, nullptr, nullptr, nullptr, 0, t2bf);
        // mlp2 + resid + LN1(next): h += t2@W2^T + b2 ; ybf = LN1_{i+1}(h) (skip last)
        if (i < DEPTH-1)
            fgemm_kernel<false,true><<<gf, 256, 0, stream>>>(t2bf, wb_m2 + (size_t)i*CH*CH,
                    mlp_b2 + i*CH, h, h, ln1_s + (i+1)*CH, ln1_b + (i+1)*CH, 1, ybf);
        else
            fgemm_kernel<false,true><<<gf, 256, 0, stream>>>(t2bf, wb_m2 + (size_t)i*CH*CH,
                    mlp_b2 + i*CH, h, h, nullptr, nullptr, 0, nullptr);
    }
    hipMemcpyAsync(d_out, h, S1*sizeof(float), hipMemcpyDeviceToDevice, stream);
}

// Round 8
// 836.825 us; speedup vs baseline: 5.6455x; 1.2211x over previous
//
#include <hip/hip_runtime.h>
#include <hip/hip_bf16.h>
#include <math.h>

#define BATCH 64
#define SEQ   256
#define CH    384
#define NHEAD 8
#define HD    48
#define DEPTH 6
#define NTOK  (BATCH*SEQ)   // 16384
#define C3    (3*CH)        // 1152
#define LN_EPS 1e-5f
#define ATT_SCALE 0.14433756729740643f  // 48^-0.5

typedef __attribute__((ext_vector_type(8)))  short bf16x8;
typedef __attribute__((ext_vector_type(4)))  float f32x4;
typedef __attribute__((ext_vector_type(16))) float f32x16;

__device__ __forceinline__ ushort f2bf(float f) {
    __hip_bfloat16 h = __float2bfloat16(f);
    return *(ushort*)&h;
}
__device__ __forceinline__ float bfu2f(ushort u) {
    uint t = ((uint)u) << 16;
    union { uint u; float f; } c; c.u = t; return c.f;
}
__device__ __forceinline__ uint pk2(float a, float b) {
    return (uint)f2bf(a) | ((uint)f2bf(b) << 16);
}

#define AS1(p) ((const __attribute__((address_space(1))) void*)(p))
#define AS3(p) ((__attribute__((address_space(3))) void*)(uintptr_t)(p))
#define WAITVMC(N) asm volatile("s_waitcnt vmcnt(" #N ")" ::: "memory")
#define TAILSYNC() do { \
    asm volatile("s_waitcnt lgkmcnt(0)" ::: "memory"); \
    __builtin_amdgcn_sched_barrier(0); \
    __builtin_amdgcn_s_barrier(); } while (0)

// ---------------- fp32 -> bf16 bulk convert ----------------
__global__ void f2bf4_kernel(const float* __restrict__ in, ushort* __restrict__ out) {
    int i = (blockIdx.x*256 + threadIdx.x)*4;
    float4 v = *(const float4*)(in + i);
    ushort4 o;
    o.x = f2bf(v.x); o.y = f2bf(v.y); o.z = f2bf(v.z); o.w = f2bf(v.w);
    *(ushort4*)(out + i) = o;
}

// ---------------- rope cos/sin table ----------------
__global__ void rope_table_kernel(float2* __restrict__ tbl) {
    int pos = threadIdx.x;
    for (int j = 0; j < 24; ++j) {
        float freq = exp2f(-(float)j * (13.287712379549449f / 24.0f));
        float ang = (float)pos * freq;
        float s, c;
        sincosf(ang, &s, &c);
        tbl[pos*24 + j] = make_float2(c, s);
    }
}

// ---------------- embed stage 1 -> bf16 ----------------
__global__ void embed1_kernel(const float* __restrict__ x, const float* __restrict__ w1,
                              const float* __restrict__ b1, ushort* __restrict__ out) {
    int idx = blockIdx.x*256 + threadIdx.x;
    int m = idx / CH, c = idx - m*CH;
    float v = x[m*2]*w1[c*2] + x[m*2+1]*w1[c*2+1] + b1[c];
    out[idx] = f2bf(fmaxf(v, 0.f));
}

// ---------------- LN-affine weight prep: W' = gam .* W (bf16), uv = {u, v(+bias)} ----------------
// wave per row; lanes 0..47 x 8 cols
__global__ __launch_bounds__(256) void prep_kernel(
        const float* __restrict__ Wsrc, const float* __restrict__ gam,
        const float* __restrict__ bet, const float* __restrict__ bias,
        int npl, ushort* __restrict__ Wdst, float2* __restrict__ uvout) {
    int rr   = blockIdx.x*4 + (threadIdx.x >> 6);
    int lane = threadIdx.x & 63;
    int layer = rr / npl;
    const float* wp = Wsrc + (size_t)rr*CH;
    const float* gp = gam + layer*CH;
    const float* bp = bet + layer*CH;
    float u = 0.f, vv = 0.f;
    if (lane < 48) {
        int c0 = lane*8;
        float w8[8];
        *(float4*)&w8[0] = *(const float4*)(wp + c0);
        *(float4*)&w8[4] = *(const float4*)(wp + c0 + 4);
        union { ushort us[8]; bf16x8 v; } o;
        #pragma unroll
        for (int j = 0; j < 8; ++j) {
            float wg = w8[j] * gp[c0+j];
            u  += wg;
            vv += bp[c0+j] * w8[j];
            o.us[j] = f2bf(wg);
        }
        *(bf16x8*)(Wdst + (size_t)rr*CH + c0) = o.v;
    }
    #pragma unroll
    for (int o = 1; o < 64; o <<= 1) { u += __shfl_xor(u, o); vv += __shfl_xor(vv, o); }
    if (lane == 0) {
        if (bias) vv += bias[rr];
        uvout[rr] = make_float2(u, vv);
    }
}

// ---------------- row stats: mu, rsqrt(var+eps) from bf16 h ----------------
__global__ __launch_bounds__(256) void stats_kernel(const ushort* __restrict__ hbf,
                                                    float2* __restrict__ rstat) {
    int row  = blockIdx.x*4 + (threadIdx.x >> 6);
    int lane = threadIdx.x & 63;
    float v[8];
    float s = 0.f;
    bool act = lane < 48;
    if (act) {
        union { ushort us[8]; bf16x8 v; } x;
        x.v = *(const bf16x8*)(hbf + (size_t)row*CH + lane*8);
        #pragma unroll
        for (int j = 0; j < 8; ++j) { v[j] = bfu2f(x.us[j]); s += v[j]; }
    }
    #pragma unroll
    for (int o = 1; o < 64; o <<= 1) s += __shfl_xor(s, o);
    float mu = s * (1.0f/CH);
    float q = 0.f;
    if (act) {
        #pragma unroll
        for (int j = 0; j < 8; ++j) { float d = v[j]-mu; q += d*d; }
    }
    #pragma unroll
    for (int o = 1; o < 64; o <<= 1) q += __shfl_xor(q, o);
    if (lane == 0) rstat[row] = make_float2(mu, rsqrtf(q*(1.0f/CH) + LN_EPS));
}

// ---------------- uniform bf16 MFMA NT-GEMM: BM=128,BN=128,BK=64, ring-2, T2-swizzled ----------------
// LNAFF: out = inv_m*(S - mu_m*u_n) + v_n [relu] -> bf16   (LN folded into W'=gam.*W)
// else : out = S + bias [+resid] -> h fp32 + hbf bf16
template<bool LNAFF, bool RELU, bool RESID>
__global__ __launch_bounds__(256) void gemm_kernel(
        const ushort* __restrict__ A,      // [M][CH] bf16
        const ushort* __restrict__ W,      // [N][CH] bf16 (W' for LNAFF)
        const float*  __restrict__ bias,   // [N] (HPROD)
        const float2* __restrict__ uv,     // [N] (LNAFF)
        const float2* __restrict__ rstat,  // [M] (LNAFF)
        const float*  __restrict__ resid,  // [M][CH] fp32 (RESID)
        float*  __restrict__ hout,         // fp32 out (HPROD)
        ushort* __restrict__ bout,         // bf16 out
        int ldo) {
    __shared__ __align__(16) ushort As[2][8192];   // 16KB x2
    __shared__ __align__(16) ushort Bs[2][8192];   // 16KB x2
    const int tid  = threadIdx.x;
    const int lane = tid & 63;
    const int w    = tid >> 6;
    const int l15  = lane & 15;
    const int g    = lane >> 4;
    const int wr   = (w >> 1) * 64;
    const int wc   = (w & 1) * 64;
    const int m0   = blockIdx.y * 128;
    const int n0   = blockIdx.x * 128;

    // staging: chunk = 8 rows x 64 cols (1KB). lane L -> row L/8, swizzled col ((L%8)^(L/8&7))*8.
    // LDS dest is wave-uniform base; HW scatters lane*16 -> phys col (L%8)*16 of row L/8.
    const int srow = lane >> 3;
    const int scol = ((lane & 7) ^ srow) * 8;
    auto stage = [&](int pb, int t) {
        int k0 = t*64;
        #pragma unroll
        for (int c = 0; c < 8; ++c) {
            int chunk = w + c*4;   // 0..31
            if (chunk < 16) {
                const ushort* gp = A + (size_t)(m0 + chunk*8 + srow)*CH + k0 + scol;
                __builtin_amdgcn_global_load_lds(AS1(gp), AS3(&As[pb][chunk*512]), 16, 0, 0);
            } else {
                const ushort* gp = W + (size_t)(n0 + (chunk-16)*8 + srow)*CH + k0 + scol;
                __builtin_amdgcn_global_load_lds(AS1(gp), AS3(&Bs[pb][(chunk-16)*512]), 16, 0, 0);
            }
        }
    };

    f32x4 acc[4][4] = {};
    const int xm = (l15 & 7) << 4;     // read-side XOR (row&7)<<4

    stage(0, 0);
    for (int t = 0; t < 6; ++t) {
        if (t + 1 < 6) stage((t+1)&1, t+1);        // issue-early prefetch
        if (t < 5) { WAITVMC(8); } else { WAITVMC(0); }  // own tile-t loads done
        __builtin_amdgcn_s_barrier();               // all waves' tile-t loads done
        const int pb = t & 1;
        #pragma unroll
        for (int kk = 0; kk < 2; ++kk) {
            bf16x8 a[4], b[4];
            #pragma unroll
            for (int i = 0; i < 4; ++i)
                a[i] = *(const bf16x8*)((const char*)As[pb]
                        + (wr + i*16 + l15)*128 + ((kk*64 + 16*g) ^ xm));
            #pragma unroll
            for (int j = 0; j < 4; ++j)
                b[j] = *(const bf16x8*)((const char*)Bs[pb]
                        + (wc + j*16 + l15)*128 + ((kk*64 + 16*g) ^ xm));
            #pragma unroll
            for (int i = 0; i < 4; ++i)
                #pragma unroll
                for (int j = 0; j < 4; ++j)
                    acc[i][j] = __builtin_amdgcn_mfma_f32_16x16x32_bf16(a[i], b[j], acc[i][j], 0, 0, 0);
        }
        TAILSYNC();    // ds_reads retired before next-iter overwrite
    }

    const int cbase = n0 + wc + l15;
    const int rbase = m0 + wr + g*4;
    if (LNAFF) {
        float2 uvv[4];
        #pragma unroll
        for (int j = 0; j < 4; ++j) uvv[j] = uv[cbase + j*16];
        #pragma unroll
        for (int i = 0; i < 4; ++i)
            #pragma unroll
            for (int r = 0; r < 4; ++r) {
                int m = rbase + i*16 + r;
                float2 st = rstat[m];
                #pragma unroll
                for (int j = 0; j < 4; ++j) {
                    float v = st.y*(acc[i][j][r] - st.x*uvv[j].x) + uvv[j].y;
                    if (RELU) v = fmaxf(v, 0.f);
                    bout[(size_t)m*ldo + cbase + j*16] = f2bf(v);
                }
            }
    } else {
        float bj[4];
        #pragma unroll
        for (int j = 0; j < 4; ++j) bj[j] = bias[cbase + j*16];
        #pragma unroll
        for (int i = 0; i < 4; ++i)
            #pragma unroll
            for (int r = 0; r < 4; ++r) {
                int m = rbase + i*16 + r;
                #pragma unroll
                for (int j = 0; j < 4; ++j) {
                    int n = cbase + j*16;
                    float v = acc[i][j][r] + bj[j];
                    if (RESID) v += resid[(size_t)m*CH + n];
                    hout[(size_t)m*CH + n] = v;
                    bout[(size_t)m*CH + n] = f2bf(v);
                }
            }
    }
}

// ---------------- MFMA attention (bf16 qkv input): block=(b,h), 8 waves, wave=32 q-rows ----------------
__global__ __launch_bounds__(512) void attn_kernel(
        const ushort* __restrict__ qkv, const float* __restrict__ mask,
        const float2* __restrict__ tbl, ushort* __restrict__ obuf) {
    __shared__ __align__(16) ushort Kf[8*3*64*8];   // 24 KB
    __shared__ __align__(16) ushort Vf[2*16*64*8];  // 32 KB
    __shared__ float Ms[SEQ];

    const int bid = blockIdx.x;
    const int b   = bid >> 3;
    const int hh  = bid & 7;
    const int tid = threadIdx.x;
    const int lane = tid & 63;
    const int hi   = (lane >> 5);
    const int q5   = lane & 31;
    const ushort* base = qkv + (size_t)b*SEQ*C3;

    {
        int t   = tid >> 6;
        int row = t*32 + q5;
        const ushort* kp = base + (size_t)row*C3 + CH + hh*HD;
        #pragma unroll
        for (int s = 0; s < 3; ++s) {
            union { ushort us[8]; bf16x8 v; } raw;
            raw.v = *(const bf16x8*)(kp + s*16 + hi*8);
            union { uint w[4]; bf16x8 v; } u;
            #pragma unroll
            for (int p = 0; p < 4; ++p) {
                float2 cs = tbl[row*24 + s*8 + hi*4 + p];
                float xu = bfu2f(raw.us[2*p]), xe = bfu2f(raw.us[2*p+1]);
                u.w[p] = pk2(xu*cs.x - xe*cs.y, xu*cs.y + xe*cs.x);
            }
            *(bf16x8*)&Kf[((t*3 + s)*64 + lane)*8] = u.v;
        }
    }
    {
        #pragma unroll
        for (int p = 0; p < 4; ++p) {
            int dt = p >> 1;
            int sp = (tid >> 6)*2 + (p & 1);
            int dd = dt*32 + q5;
            union { uint w[4]; bf16x8 v; } u;
            if (dd < HD) {
                const ushort* vp = base + (size_t)(sp*16 + hi*8)*C3 + 2*CH + hh*HD + dd;
                #pragma unroll
                for (int k = 0; k < 4; ++k)
                    u.w[k] = (uint)vp[(2*k)*C3] | ((uint)vp[(2*k+1)*C3] << 16);
            } else {
                u.w[0] = u.w[1] = u.w[2] = u.w[3] = 0u;
            }
            *(bf16x8*)&Vf[((dt*16 + sp)*64 + lane)*8] = u.v;
        }
    }
    if (tid < SEQ) Ms[tid] = mask[b*SEQ + tid];

    const int wv    = tid >> 6;
    const int qrow  = wv*32 + q5;
    bf16x8 qf[3];
    {
        const ushort* qp = base + (size_t)qrow*C3 + hh*HD;
        #pragma unroll
        for (int s = 0; s < 3; ++s) {
            union { ushort us[8]; bf16x8 v; } raw;
            raw.v = *(const bf16x8*)(qp + s*16 + hi*8);
            union { uint w[4]; bf16x8 v; } u;
            #pragma unroll
            for (int p = 0; p < 4; ++p) {
                float2 cs = tbl[qrow*24 + s*8 + hi*4 + p];
                float xu = bfu2f(raw.us[2*p]), xe = bfu2f(raw.us[2*p+1]);
                u.w[p] = pk2((xu*cs.x - xe*cs.y)*ATT_SCALE, (xu*cs.y + xe*cs.x)*ATT_SCALE);
            }
            qf[s] = u.v;
        }
    }
    __syncthreads();

    f32x16 st[8] = {};
    #pragma unroll
    for (int t = 0; t < 8; ++t)
        #pragma unroll
        for (int s = 0; s < 3; ++s) {
            bf16x8 af = *(const bf16x8*)&Kf[((t*3 + s)*64 + lane)*8];
            st[t] = __builtin_amdgcn_mfma_f32_32x32x16_bf16(af, qf[s], st[t], 0, 0, 0);
        }

    float mx = -1e30f;
    #pragma unroll
    for (int t = 0; t < 8; ++t)
        #pragma unroll
        for (int r = 0; r < 16; ++r) {
            int kt = t*32 + (r & 3) + 8*(r >> 2) + 4*hi;
            float s = st[t][r] + Ms[kt];
            st[t][r] = s;
            mx = fmaxf(mx, s);
        }
    mx = fmaxf(mx, __shfl_xor(mx, 32));
    float sum = 0.f;
    #pragma unroll
    for (int t = 0; t < 8; ++t)
        #pragma unroll
        for (int r = 0; r < 16; ++r) {
            float p = __expf(st[t][r] - mx);
            st[t][r] = p;
            sum += p;
        }
    sum += __shfl_xor(sum, 32);

    f32x16 oacc[2] = {};
    #pragma unroll
    for (int t = 0; t < 8; ++t) {
        uint w[4][2];
        #pragma unroll
        for (int g = 0; g < 4; ++g) {
            w[g][0] = pk2(st[t][g*4+0], st[t][g*4+1]);
            w[g][1] = pk2(st[t][g*4+2], st[t][g*4+3]);
        }
        #pragma unroll
        for (int o = 0; o < 2; ++o) {
            uint x0 = __shfl_xor(hi ? w[2*o][0] : w[2*o+1][0], 32);
            uint x1 = __shfl_xor(hi ? w[2*o][1] : w[2*o+1][1], 32);
            union { uint w[4]; bf16x8 v; } pf;
            if (hi == 0) { pf.w[0] = w[2*o][0]; pf.w[1] = w[2*o][1]; pf.w[2] = x0; pf.w[3] = x1; }
            else         { pf.w[0] = x0; pf.w[1] = x1; pf.w[2] = w[2*o+1][0]; pf.w[3] = w[2*o+1][1]; }
            int sp = t*2 + o;
            #pragma unroll
            for (int dt = 0; dt < 2; ++dt) {
                bf16x8 vf = *(const bf16x8*)&Vf[((dt*16 + sp)*64 + lane)*8];
                oacc[dt] = __builtin_amdgcn_mfma_f32_32x32x16_bf16(vf, pf.v, oacc[dt], 0, 0, 0);
            }
        }
    }

    float inv = 1.f / sum;
    ushort* op = obuf + ((size_t)(b*SEQ + qrow))*CH + hh*HD;
    #pragma unroll
    for (int dt = 0; dt < 2; ++dt)
        #pragma unroll
        for (int rg = 0; rg < 4; ++rg) {
            int d0 = dt*32 + rg*8 + hi*4;
            if (d0 < HD) {
                uint2 val;
                val.x = pk2(oacc[dt][rg*4+0]*inv, oacc[dt][rg*4+1]*inv);
                val.y = pk2(oacc[dt][rg*4+2]*inv, oacc[dt][rg*4+3]*inv);
                *(uint2*)(op + d0) = val;
            }
        }
}

// ---------------- launcher ----------------
extern "C" void kernel_launch(void* const* d_in, const int* in_sizes, int n_in,
                              void* d_out, int out_size, void* d_ws, size_t ws_size,
                              hipStream_t stream) {
    const float* x      = (const float*)d_in[0];
    const float* mask   = (const float*)d_in[1];
    const float* emb_w1 = (const float*)d_in[2];
    const float* emb_b1 = (const float*)d_in[3];
    const float* emb_w2 = (const float*)d_in[4];
    const float* emb_b2 = (const float*)d_in[5];
    const float* qkv_w  = (const float*)d_in[6];
    const float* proj_w = (const float*)d_in[7];
    const float* proj_b = (const float*)d_in[8];
    const float* mlp_w1 = (const float*)d_in[9];
    const float* mlp_b1 = (const float*)d_in[10];
    const float* mlp_w2 = (const float*)d_in[11];
    const float* mlp_b2 = (const float*)d_in[12];
    const float* ln1_s  = (const float*)d_in[13];
    const float* ln1_b  = (const float*)d_in[14];
    const float* ln2_s  = (const float*)d_in[15];
    const float* ln2_b  = (const float*)d_in[16];

    const size_t S1 = (size_t)NTOK*CH;
    float*  h     = (float*)d_ws;               // fp32 [NTOK][CH]
    ushort* hbf   = (ushort*)(h + S1);          // bf16 shadow of h
    ushort* qkvbf = hbf + S1;                   // bf16 [NTOK][C3]
    ushort* ybf   = qkvbf + 3*S1;               // embed1 out
    ushort* t2bf  = ybf  + S1;
    ushort* obf   = t2bf + S1;
    ushort* wb_emb2 = obf + S1;                      // 147456
    ushort* wb_proj = wb_emb2 + 147456;              // 884736
    ushort* wb_m2   = wb_proj + 884736;              // 884736
    ushort* wqkvp   = wb_m2   + 884736;              // 2654208 (gam1 .* qkv_w)
    ushort* wm1p    = wqkvp   + 2654208;             // 884736  (gam2 .* mlp_w1)
    float2* uv_qkv  = (float2*)(wm1p + 884736);      // 6912
    float2* uv_m1   = uv_qkv + 6912;                 // 2304
    float2* rstat   = uv_m1  + 2304;                 // 16384
    float*  tbl     = (float*)(rstat + 16384);

    dim3 gqkv(9, 128);      // N=1152
    dim3 g384(3, 128);      // N=384

    rope_table_kernel<<<1, 256, 0, stream>>>((float2*)tbl);
    f2bf4_kernel<<<144, 256, 0, stream>>>(emb_w2, wb_emb2);
    f2bf4_kernel<<<864, 256, 0, stream>>>(proj_w, wb_proj);
    f2bf4_kernel<<<864, 256, 0, stream>>>(mlp_w2, wb_m2);
    prep_kernel<<<1728, 256, 0, stream>>>(qkv_w,  ln1_s, ln1_b, nullptr, C3, wqkvp, uv_qkv);
    prep_kernel<<<576,  256, 0, stream>>>(mlp_w1, ln2_s, ln2_b, mlp_b1,  CH, wm1p,  uv_m1);

    embed1_kernel<<<(NTOK*CH)/256, 256, 0, stream>>>(x, emb_w1, emb_b1, ybf);
    gemm_kernel<false,false,false><<<g384, 256, 0, stream>>>(ybf, wb_emb2, emb_b2,
            nullptr, nullptr, nullptr, h, hbf, CH);
    stats_kernel<<<NTOK/4, 256, 0, stream>>>(hbf, rstat);

    for (int i = 0; i < DEPTH; ++i) {
        gemm_kernel<true,false,false><<<gqkv, 256, 0, stream>>>(hbf,
                wqkvp + (size_t)i*C3*CH, nullptr, uv_qkv + i*C3, rstat,
                nullptr, nullptr, qkvbf, C3);
        attn_kernel<<<BATCH*NHEAD, 512, 0, stream>>>(qkvbf, mask, (const float2*)tbl, obf);
        gemm_kernel<false,false,true><<<g384, 256, 0, stream>>>(obf,
                wb_proj + (size_t)i*CH*CH, proj_b + i*CH, nullptr, nullptr,
                h, h, hbf, CH);
        stats_kernel<<<NTOK/4, 256, 0, stream>>>(hbf, rstat);
        gemm_kernel<true,true,false><<<g384, 256, 0, stream>>>(hbf,
                wm1p + (size_t)i*CH*CH, nullptr, uv_m1 + i*CH, rstat,
                nullptr, nullptr, t2bf, CH);
        gemm_kernel<false,false,true><<<g384, 256, 0, stream>>>(t2bf,
                wb_m2 + (size_t)i*CH*CH, mlp_b2 + i*CH, nullptr, nullptr,
                h, h, hbf, CH);
        if (i < DEPTH-1) stats_kernel<<<NTOK/4, 256, 0, stream>>>(hbf, rstat);
    }
    hipMemcpyAsync(d_out, h, S1*sizeof(float), hipMemcpyDeviceToDevice, stream);
}